// Round 4
// baseline (714.442 us; speedup 1.0000x reference)
//
#include <hip/hip_runtime.h>

#define HDIM 1024
#define MMEM 8192
#define TOPK 2048
#define NROWS 8192
#define LNEPS 1e-5f

typedef unsigned short ushort_t;
typedef __bf16 bf16x8 __attribute__((ext_vector_type(8)));
typedef float f32x4 __attribute__((ext_vector_type(4)));
typedef __attribute__((address_space(1))) const void GVoid;
typedef __attribute__((address_space(3))) void LVoid;

// ---------- helpers ----------
__device__ __forceinline__ ushort_t f2bf(float f) {
    union { float f; unsigned u; } c; c.f = f;
    unsigned r = c.u + 0x7fffu + ((c.u >> 16) & 1u);
    return (ushort_t)(r >> 16);
}
__device__ __forceinline__ float bf2f(ushort_t u) {
    union { unsigned u; float f; } c; c.u = ((unsigned)u) << 16; return c.f;
}
__device__ __forceinline__ float blk_red(float v, int op, float* red) {
    #pragma unroll
    for (int o = 32; o; o >>= 1) {
        float u = __shfl_down(v, o);
        v = op ? fmaxf(v, u) : v + u;
    }
    if ((threadIdx.x & 63) == 0) red[threadIdx.x >> 6] = v;
    __syncthreads();
    float r = op ? fmaxf(fmaxf(red[0], red[1]), fmaxf(red[2], red[3]))
                 : (red[0] + red[1]) + (red[2] + red[3]);
    __syncthreads();
    return r;
}

// ---------- small prep kernels ----------
__global__ __launch_bounds__(256) void sel_prep(const float* __restrict__ sp,
        const float* __restrict__ imp, const float* __restrict__ rec,
        const float* __restrict__ ac, float* __restrict__ sel) {
    __shared__ float red[4];
    float p0 = sp[0], p1 = sp[1], p2 = sp[2];
    float mx = fmaxf(p0, fmaxf(p1, p2));
    float e0 = expf(p0 - mx), e1 = expf(p1 - mx), e2 = expf(p2 - mx);
    float inv = 1.f / (e0 + e1 + e2);
    float w0 = e0 * inv, w1 = e1 * inv, w2 = e2 * inv;
    float m = -1e30f;
    for (int i = threadIdx.x; i < MMEM; i += 256) m = fmaxf(m, ac[i]);
    m = blk_red(m, 1, red);
    float rinv = 1.f / m;
    for (int i = threadIdx.x; i < MMEM; i += 256)
        sel[i] = w0 * imp[i] + w1 * rec[i] + w2 * (ac[i] * rinv);
}

// rank-based exact top-k: grid 256 blocks x 32 i's; 8 j-chunks per i.
__global__ __launch_bounds__(256) void topk_rank(const float* __restrict__ sel,
                                                 int* __restrict__ idx) {
    __shared__ float s[MMEM];        // 32 KB
    __shared__ int pc[256];
    for (int t = threadIdx.x; t < MMEM / 4; t += 256)
        reinterpret_cast<float4*>(s)[t] = reinterpret_cast<const float4*>(sel)[t];
    __syncthreads();
    const int li = threadIdx.x & 31;
    const int jc = threadIdx.x >> 5;
    const int i  = blockIdx.x * 32 + li;
    const float si = s[i];
    int cnt = 0;
    const float4* sv = reinterpret_cast<const float4*>(s) + jc * 256;
    #pragma unroll 4
    for (int t = 0; t < 256; ++t) {
        float4 v = sv[t];
        int j0 = jc * 1024 + t * 4;
        cnt += (v.x > si) || (v.x == si && (j0 + 0) < i);
        cnt += (v.y > si) || (v.y == si && (j0 + 1) < i);
        cnt += (v.z > si) || (v.z == si && (j0 + 2) < i);
        cnt += (v.w > si) || (v.w == si && (j0 + 3) < i);
    }
    pc[threadIdx.x] = cnt;
    __syncthreads();
    if (threadIdx.x < 32) {
        int r = 0;
        #pragma unroll
        for (int c = 0; c < 8; ++c) r += pc[c * 32 + threadIdx.x];
        if (r < TOPK) idx[r] = blockIdx.x * 32 + threadIdx.x;
    }
}

__global__ __launch_bounds__(256) void gather_ln(const float* __restrict__ mem_keys,
        const int* __restrict__ idx, const float* __restrict__ g,
        const float* __restrict__ b, ushort_t* __restrict__ out) {
    __shared__ float red[4];
    int src = idx[blockIdx.x] & (MMEM - 1);
    const float* x = mem_keys + (size_t)src * HDIM;
    float4 v = reinterpret_cast<const float4*>(x)[threadIdx.x];
    float s = v.x + v.y + v.z + v.w;
    float ss = v.x*v.x + v.y*v.y + v.z*v.z + v.w*v.w;
    s  = blk_red(s, 0, red);
    ss = blk_red(ss, 0, red);
    float mu = s * (1.f / HDIM);
    float var = ss * (1.f / HDIM) - mu * mu;
    float rstd = rsqrtf(var + LNEPS);
    int c = threadIdx.x * 4;
    ushort4 o;
    o.x = f2bf((v.x - mu) * rstd * g[c+0] + b[c+0]);
    o.y = f2bf((v.y - mu) * rstd * g[c+1] + b[c+1]);
    o.z = f2bf((v.z - mu) * rstd * g[c+2] + b[c+2]);
    o.w = f2bf((v.w - mu) * rstd * g[c+3] + b[c+3]);
    *reinterpret_cast<ushort4*>(out + (size_t)blockIdx.x * HDIM + c) = o;
}

__global__ __launch_bounds__(256) void cvt_bf16(const float* __restrict__ in,
                                                ushort_t* __restrict__ out) {
    size_t i = ((size_t)blockIdx.x * 256 + threadIdx.x) * 4;
    float4 v = *reinterpret_cast<const float4*>(in + i);
    ushort4 o = { f2bf(v.x), f2bf(v.y), f2bf(v.z), f2bf(v.w) };
    *reinterpret_cast<ushort4*>(out + i) = o;
}

__global__ __launch_bounds__(256) void cvt_x_cat(const float* __restrict__ x,
                                                 ushort_t* __restrict__ cat) {
    size_t i = ((size_t)blockIdx.x * 256 + threadIdx.x) * 4;
    size_t row = i >> 10, col = i & 1023;
    float4 v = *reinterpret_cast<const float4*>(x + i);
    ushort4 o = { f2bf(v.x), f2bf(v.y), f2bf(v.z), f2bf(v.w) };
    *reinterpret_cast<ushort4*>(cat + row * 2048 + col) = o;
}

__global__ __launch_bounds__(256) void softmax_rows(ushort_t* __restrict__ sc) {
    __shared__ float red[4];
    ushort_t* p = sc + (size_t)blockIdx.x * 2048 + threadIdx.x * 8;
    ushort4 a = reinterpret_cast<const ushort4*>(p)[0];
    ushort4 bq = reinterpret_cast<const ushort4*>(p)[1];
    float v[8] = { bf2f(a.x), bf2f(a.y), bf2f(a.z), bf2f(a.w),
                   bf2f(bq.x), bf2f(bq.y), bf2f(bq.z), bf2f(bq.w) };
    float mx = v[0];
    #pragma unroll
    for (int j = 1; j < 8; ++j) mx = fmaxf(mx, v[j]);
    mx = blk_red(mx, 1, red);
    float s = 0.f;
    #pragma unroll
    for (int j = 0; j < 8; ++j) { v[j] = expf(v[j] - mx); s += v[j]; }
    s = blk_red(s, 0, red);
    float inv = 1.f / s;
    ushort4 o1 = { f2bf(v[0]*inv), f2bf(v[1]*inv), f2bf(v[2]*inv), f2bf(v[3]*inv) };
    ushort4 o2 = { f2bf(v[4]*inv), f2bf(v[5]*inv), f2bf(v[6]*inv), f2bf(v[7]*inv) };
    reinterpret_cast<ushort4*>(p)[0] = o1;
    reinterpret_cast<ushort4*>(p)[1] = o2;
}

// in-place LN(2048) + exact gelu on bf16 rows; grid = 8192
__global__ __launch_bounds__(256) void ln_gelu(ushort_t* h1,
        const float* __restrict__ g, const float* __restrict__ b) {
    __shared__ float red[4];
    ushort_t* p = h1 + (size_t)blockIdx.x * 2048 + threadIdx.x * 8;
    ushort4 a = reinterpret_cast<const ushort4*>(p)[0];
    ushort4 c = reinterpret_cast<const ushort4*>(p)[1];
    float v[8] = { bf2f(a.x), bf2f(a.y), bf2f(a.z), bf2f(a.w),
                   bf2f(c.x), bf2f(c.y), bf2f(c.z), bf2f(c.w) };
    float s = 0.f, ss = 0.f;
    #pragma unroll
    for (int j = 0; j < 8; ++j) { s += v[j]; ss += v[j]*v[j]; }
    s  = blk_red(s, 0, red);
    ss = blk_red(ss, 0, red);
    float mu = s * (1.f / 2048.f);
    float var = ss * (1.f / 2048.f) - mu * mu;
    float rstd = rsqrtf(var + LNEPS);
    int c0 = threadIdx.x * 8;
    ushort_t o[8];
    #pragma unroll
    for (int j = 0; j < 8; ++j) {
        float xn = (v[j] - mu) * rstd * g[c0 + j] + b[c0 + j];
        float ge = 0.5f * xn * (1.f + erff(xn * 0.70710678118654752f));
        o[j] = f2bf(ge);
    }
    ushort4 o1 = { o[0], o[1], o[2], o[3] };
    ushort4 o2 = { o[4], o[5], o[6], o[7] };
    reinterpret_cast<ushort4*>(p)[0] = o1;
    reinterpret_cast<ushort4*>(p)[1] = o2;
}

// out = LN(x + gate*integ); gate may alias out (read-before-write per thread)
__global__ __launch_bounds__(256) void final_ln(const float* __restrict__ x,
        const float* gate, const ushort_t* __restrict__ integ,
        const float* __restrict__ g, const float* __restrict__ b,
        float* out) {
    __shared__ float red[4];
    size_t base = (size_t)blockIdx.x * HDIM + threadIdx.x * 4;
    float4 xv = *reinterpret_cast<const float4*>(x + base);
    float4 gv = *reinterpret_cast<const float4*>(gate + base);
    ushort4 iv = *reinterpret_cast<const ushort4*>(integ + base);
    float v[4] = { xv.x + gv.x*bf2f(iv.x), xv.y + gv.y*bf2f(iv.y),
                   xv.z + gv.z*bf2f(iv.z), xv.w + gv.w*bf2f(iv.w) };
    float s = v[0]+v[1]+v[2]+v[3];
    float ss = v[0]*v[0]+v[1]*v[1]+v[2]*v[2]+v[3]*v[3];
    s  = blk_red(s, 0, red);
    ss = blk_red(ss, 0, red);
    float mu = s * (1.f / HDIM);
    float var = ss * (1.f / HDIM) - mu * mu;
    float rstd = rsqrtf(var + LNEPS);
    int c = threadIdx.x * 4;
    float4 o;
    o.x = (v[0] - mu) * rstd * g[c+0] + b[c+0];
    o.y = (v[1] - mu) * rstd * g[c+1] + b[c+1];
    o.z = (v[2] - mu) * rstd * g[c+2] + b[c+2];
    o.w = (v[3] - mu) * rstd * g[c+3] + b[c+3];
    *reinterpret_cast<float4*>(out + base) = o;
}

// ---------- small-shape MFMA GEMM (128x128, single-phase) ----------
// EPI: 0=f32, 1=bf16, 2=sigmoid->f32 ; BIAS: 0=none, 1=per-col, 2=per-row
template<int EPI, int BIAS>
__global__ __launch_bounds__(256, 2)
void gemm_bt(const ushort_t* __restrict__ A, const ushort_t* __restrict__ B,
             const float* __restrict__ bias, void* __restrict__ Cv,
             int K, int lda, int ldb, int ldc,
             long long sA1, long long sA2, long long sAz,
             long long sB1, long long sB2, long long sBz,
             long long sC1, long long sC2, long long sCz,
             int z2n, int zbase, float scale)
{
    __shared__ __align__(16) ushort_t As[8192];   // 128 x 64
    __shared__ __align__(16) ushort_t Bs[8192];   // 128 x 64
    const int zz = blockIdx.z;
    const int zg = zz + zbase;
    const int z1 = zg / z2n, z2 = zg - z1 * z2n;
    A += (size_t)(z1 * sA1 + z2 * sA2 + zz * sAz);
    B += (size_t)(z1 * sB1 + z2 * sB2 + zz * sBz);
    const size_t cOff = (size_t)(z1 * sC1 + z2 * sC2 + zz * sCz);
    const int m0 = blockIdx.y * 128, n0 = blockIdx.x * 128;
    const int tid = threadIdx.x;
    const int w = tid >> 6, l = tid & 63;
    const int wm = w >> 1, wn = w & 1;

    f32x4 acc[4][4] = {};

    const int srow = l >> 3;
    const int scol = ((l & 7) ^ srow) << 3;   // elements

    for (int k0 = 0; k0 < K; k0 += 64) {
        #pragma unroll
        for (int i = 0; i < 4; ++i) {
            const int c = i * 4 + w;
            const int row = c * 8 + srow;
            const ushort_t* ga = A + (size_t)(m0 + row) * lda + (k0 + scol);
            const ushort_t* gb = B + (size_t)(n0 + row) * ldb + (k0 + scol);
            __builtin_amdgcn_global_load_lds((GVoid*)ga, (LVoid*)(As + c * 512), 16, 0, 0);
            __builtin_amdgcn_global_load_lds((GVoid*)gb, (LVoid*)(Bs + c * 512), 16, 0, 0);
        }
        __syncthreads();
        #pragma unroll
        for (int kk = 0; kk < 2; ++kk) {
            bf16x8 af[4], bfv[4];
            #pragma unroll
            for (int m = 0; m < 4; ++m) {
                const int row = wm * 64 + m * 16 + (l & 15);
                const int cb = ((kk * 64) + ((l >> 4) * 16)) ^ ((row & 7) << 4);
                af[m] = *reinterpret_cast<const bf16x8*>(
                    reinterpret_cast<const char*>(As) + row * 128 + cb);
            }
            #pragma unroll
            for (int n = 0; n < 4; ++n) {
                const int row = wn * 64 + n * 16 + (l & 15);
                const int cb = ((kk * 64) + ((l >> 4) * 16)) ^ ((row & 7) << 4);
                bfv[n] = *reinterpret_cast<const bf16x8*>(
                    reinterpret_cast<const char*>(Bs) + row * 128 + cb);
            }
            #pragma unroll
            for (int m = 0; m < 4; ++m)
                #pragma unroll
                for (int n = 0; n < 4; ++n)
                    acc[m][n] = __builtin_amdgcn_mfma_f32_16x16x32_bf16(
                        af[m], bfv[n], acc[m][n], 0, 0, 0);
        }
        __syncthreads();
    }

    #pragma unroll
    for (int m = 0; m < 4; ++m) {
        const int grow = m0 + wm * 64 + m * 16 + ((l >> 4) << 2);
        #pragma unroll
        for (int n = 0; n < 4; ++n) {
            const int gcol = n0 + wn * 64 + n * 16 + (l & 15);
            float bc = (BIAS == 1) ? bias[gcol] : 0.f;
            #pragma unroll
            for (int j = 0; j < 4; ++j) {
                float v = acc[m][n][j] * scale;
                if (BIAS == 1) v += bc;
                if (BIAS == 2) v += bias[grow + j];
                if (EPI == 2) v = 1.f / (1.f + expf(-v));
                const size_t off = cOff + (size_t)(grow + j) * ldc + gcol;
                if (EPI == 1) ((ushort_t*)Cv)[off] = f2bf(v);
                else          ((float*)Cv)[off]    = v;
            }
        }
    }
}

// ---------- big MFMA GEMM: 256 x BN tile, 8 waves, counted-vmcnt pipeline ----
// M multiple of 256, N multiple of BN, K multiple of 128 (NT even not required,
// NT >= 2). C = scale*(A . B^T) + bias.
template<int BN, int EPI, int BIAS>
__global__ __launch_bounds__(512, 2)
void gemm256(const ushort_t* __restrict__ A, const ushort_t* __restrict__ B,
             const float* __restrict__ bias, void* __restrict__ Cv,
             int K, int lda, int ldb, int ldc,
             long long sA1, long long sA2, long long sAz,
             long long sB1, long long sB2, long long sBz,
             long long sC1, long long sC2, long long sCz,
             int z2n, int zbase, float scale)
{
    constexpr int NF   = BN / 64;     // n-frags per wave
    constexpr int LB   = BN / 64;     // B-stage instrs per thread
    constexpr int LTOT = 4 + LB;      // loads per tile per thread
    __shared__ __align__(16) ushort_t As[2][256 * 64];
    __shared__ __align__(16) ushort_t Bs[2][BN * 64];

    const int zz = blockIdx.z;
    const int zg = zz + zbase;
    const int z1 = zg / z2n, z2 = zg - z1 * z2n;
    A += (size_t)(z1 * sA1 + z2 * sA2 + zz * sAz);
    B += (size_t)(z1 * sB1 + z2 * sB2 + zz * sBz);
    const size_t cOff = (size_t)(z1 * sC1 + z2 * sC2 + zz * sCz);

    const int m0 = blockIdx.y * 256, n0 = blockIdx.x * BN;
    const int tid = threadIdx.x;
    const int wid = tid >> 6, l = tid & 63;
    const int wm = wid >> 2, wn = wid & 3;     // 2 x 4 waves
    const int NT = K >> 6;

    const int srow8 = l >> 3;                       // 0..7
    const int scol  = ((l & 7) ^ srow8) << 3;       // XOR-pre-swizzled src col (elem)

    // stage K-tile t into LDS buffer p (linear dest, pre-swizzled global source)
    auto STAGE = [&](int t, int p) {
        const int k0 = t << 6;
        #pragma unroll
        for (int j = 0; j < 4; ++j) {
            const int c = j * 8 + wid;              // 0..31 -> rows c*8..c*8+7
            const int row = c * 8 + srow8;
            const ushort_t* ga = A + (size_t)(m0 + row) * lda + (k0 + scol);
            __builtin_amdgcn_global_load_lds((GVoid*)ga, (LVoid*)(&As[p][0] + c * 512), 16, 0, 0);
        }
        #pragma unroll
        for (int j = 0; j < LB; ++j) {
            const int c = j * 8 + wid;              // 0..8*LB-1
            const int row = c * 8 + srow8;
            const ushort_t* gb = B + (size_t)(n0 + row) * ldb + (k0 + scol);
            __builtin_amdgcn_global_load_lds((GVoid*)gb, (LVoid*)(&Bs[p][0] + c * 512), 16, 0, 0);
        }
    };

    f32x4 acc[8][NF] = {};

    STAGE(0, 0);
    STAGE(1, 1);
    asm volatile("s_waitcnt vmcnt(%0)" :: "i"(LTOT) : "memory");  // tile0 resident
    __builtin_amdgcn_s_barrier();
    __builtin_amdgcn_sched_barrier(0);

    for (int t = 0; t < NT; ++t) {
        const int p = t & 1;
        const char* Ab = reinterpret_cast<const char*>(&As[p][0]);
        const char* Bb = reinterpret_cast<const char*>(&Bs[p][0]);

        // B fragments for this tile (reused across both m-halves)
        bf16x8 bfv[NF][2];
        #pragma unroll
        for (int n = 0; n < NF; ++n)
            #pragma unroll
            for (int kk = 0; kk < 2; ++kk) {
                const int row = wn * (BN / 4) + n * 16 + (l & 15);
                const int cb = ((kk * 64) + ((l >> 4) * 16)) ^ ((row & 7) << 4);
                bfv[n][kk] = *reinterpret_cast<const bf16x8*>(Bb + row * 128 + cb);
            }
        #pragma unroll
        for (int mq = 0; mq < 2; ++mq) {
            bf16x8 af[4][2];
            #pragma unroll
            for (int m = 0; m < 4; ++m)
                #pragma unroll
                for (int kk = 0; kk < 2; ++kk) {
                    const int row = wm * 128 + (mq * 4 + m) * 16 + (l & 15);
                    const int cb = ((kk * 64) + ((l >> 4) * 16)) ^ ((row & 7) << 4);
                    af[m][kk] = *reinterpret_cast<const bf16x8*>(Ab + row * 128 + cb);
                }
            __builtin_amdgcn_s_setprio(1);
            #pragma unroll
            for (int m = 0; m < 4; ++m)
                #pragma unroll
                for (int n = 0; n < NF; ++n)
                    #pragma unroll
                    for (int kk = 0; kk < 2; ++kk)
                        acc[mq * 4 + m][n] = __builtin_amdgcn_mfma_f32_16x16x32_bf16(
                            af[m][kk], bfv[n][kk], acc[mq * 4 + m][n], 0, 0, 0);
            __builtin_amdgcn_s_setprio(0);
        }

        // all waves done reading buf[p] -> safe to restage it
        asm volatile("s_waitcnt lgkmcnt(0)" ::: "memory");
        __builtin_amdgcn_s_barrier();
        __builtin_amdgcn_sched_barrier(0);
        if (t + 2 < NT) {
            STAGE(t + 2, p);                         // overlaps next iteration
            asm volatile("s_waitcnt vmcnt(%0)" :: "i"(LTOT) : "memory"); // t+1 resident
            __builtin_amdgcn_s_barrier();
            __builtin_amdgcn_sched_barrier(0);
        } else if (t + 2 == NT) {
            asm volatile("s_waitcnt vmcnt(0)" ::: "memory");
            __builtin_amdgcn_s_barrier();
            __builtin_amdgcn_sched_barrier(0);
        }
    }

    #pragma unroll
    for (int mi = 0; mi < 8; ++mi) {
        const int grow = m0 + wm * 128 + mi * 16 + ((l >> 4) << 2);
        #pragma unroll
        for (int n = 0; n < NF; ++n) {
            const int gcol = n0 + wn * (BN / 4) + n * 16 + (l & 15);
            float bc = (BIAS == 1) ? bias[gcol] : 0.f;
            #pragma unroll
            for (int j = 0; j < 4; ++j) {
                float v = acc[mi][n][j] * scale;
                if (BIAS == 1) v += bc;
                if (BIAS == 2) v += bias[grow + j];
                if (EPI == 2) v = 1.f / (1.f + expf(-v));
                const size_t off = cOff + (size_t)(grow + j) * ldc + gcol;
                if (EPI == 1) ((ushort_t*)Cv)[off] = f2bf(v);
                else          ((float*)Cv)[off]    = v;
            }
        }
    }
}

// ---------- host ----------
extern "C" void kernel_launch(void* const* d_in, const int* in_sizes, int n_in,
                              void* d_out, int out_size, void* d_ws, size_t ws_size,
                              hipStream_t stream) {
    const float* x          = (const float*)d_in[0];
    const float* mem_keys   = (const float*)d_in[1];
    const float* importance = (const float*)d_in[2];
    const float* recency    = (const float*)d_in[3];
    const float* access_cnt = (const float*)d_in[4];
    const float* Wq         = (const float*)d_in[5];
    const float* bq         = (const float*)d_in[6];
    const float* in_w       = (const float*)d_in[7];
    const float* in_b       = (const float*)d_in[8];
    const float* out_w      = (const float*)d_in[9];
    const float* out_b      = (const float*)d_in[10];
    const float* gate_w     = (const float*)d_in[11];
    const float* gate_b     = (const float*)d_in[12];
    const float* int_w1     = (const float*)d_in[13];
    const float* int_b1     = (const float*)d_in[14];
    const float* int_ln_g   = (const float*)d_in[15];
    const float* int_ln_b   = (const float*)d_in[16];
    const float* int_w2     = (const float*)d_in[17];
    const float* int_b2     = (const float*)d_in[18];
    const float* ln1_g      = (const float*)d_in[19];
    const float* ln1_b      = (const float*)d_in[20];
    const float* ln2_g      = (const float*)d_in[21];
    const float* ln2_b      = (const float*)d_in[22];
    const float* sel_params = (const float*)d_in[23];

    char* ws = (char*)d_ws;
    size_t off = 0;
    auto alloc = [&](size_t bytes) -> char* {
        char* p = ws + off;
        off = (off + bytes + 255) & ~(size_t)255;
        return p;
    };

    float*    sel      = (float*)alloc(MMEM * 4);
    int*      idx      = (int*)alloc(TOPK * 4);
    ushort_t* wq_bf    = (ushort_t*)alloc((size_t)1048576 * 2);
    ushort_t* inw_bf   = (ushort_t*)alloc((size_t)3145728 * 2);
    ushort_t* outw_bf  = (ushort_t*)alloc((size_t)1048576 * 2);
    ushort_t* gatew_bf = (ushort_t*)alloc((size_t)2097152 * 2);
    ushort_t* intw1_bf = (ushort_t*)alloc((size_t)4194304 * 2);
    ushort_t* intw2_bf = (ushort_t*)alloc((size_t)2097152 * 2);
    ushort_t* mem_n    = (ushort_t*)alloc((size_t)TOPK * HDIM * 2);
    ushort_t* Kbuf     = (ushort_t*)alloc((size_t)TOPK * HDIM * 2);
    ushort_t* Vt       = (ushort_t*)alloc((size_t)HDIM * TOPK * 2);
    ushort_t* cat      = (ushort_t*)alloc((size_t)NROWS * 2048 * 2);
    ushort_t* qQ       = (ushort_t*)alloc((size_t)NROWS * 2048 * 2);
    ushort_t* qbuf     = qQ;
    ushort_t* Qbuf     = qQ + (size_t)NROWS * HDIM;
    ushort_t* h1       = qQ;                            // q/Q dead by then
    ushort_t* ctx      = (ushort_t*)alloc((size_t)NROWS * HDIM * 2);
    ushort_t* integ    = ctx;                           // ctx dead by then
    float*    gatev    = (float*)d_out;                 // overwritten at end

    int NC = 8;
    while (NC > 1 && off + (size_t)NC * 8388608 > ws_size) NC >>= 1;
    ushort_t* scores = (ushort_t*)alloc((size_t)NC * 8388608);

    cvt_bf16<<<1024, 256, 0, stream>>>(Wq, wq_bf);
    cvt_bf16<<<3072, 256, 0, stream>>>(in_w, inw_bf);
    cvt_bf16<<<1024, 256, 0, stream>>>(out_w, outw_bf);
    cvt_bf16<<<2048, 256, 0, stream>>>(gate_w, gatew_bf);
    cvt_bf16<<<4096, 256, 0, stream>>>(int_w1, intw1_bf);
    cvt_bf16<<<2048, 256, 0, stream>>>(int_w2, intw2_bf);
    cvt_x_cat<<<8192, 256, 0, stream>>>(x, cat);

    sel_prep<<<1, 256, 0, stream>>>(sel_params, importance, recency, access_cnt, sel);
    topk_rank<<<MMEM/32, 256, 0, stream>>>(sel, idx);
    gather_ln<<<TOPK, 256, 0, stream>>>(mem_keys, idx, ln1_g, ln1_b, mem_n);

    // q = x @ Wq^T + bq
    gemm256<128,1,1><<<dim3(8,32,1), 512, 0, stream>>>(cat, wq_bf, bq, qbuf,
        1024, 2048, 1024, 1024, 0,0,0, 0,0,0, 0,0,0, 1, 0, 1.f);
    // Q = q @ wq^T + bqi
    gemm256<128,1,1><<<dim3(8,32,1), 512, 0, stream>>>(qbuf, inw_bf, in_b, Qbuf,
        1024, 1024, 1024, 1024, 0,0,0, 0,0,0, 0,0,0, 1, 0, 1.f);
    // K = mem_n @ wk^T + bki   (small: keep 128^2 kernel)
    gemm_bt<1,1><<<dim3(8,16,1), 256, 0, stream>>>(mem_n, inw_bf + 1048576, in_b + 1024,
        Kbuf, 1024, 1024, 1024, 1024, 0,0,0, 0,0,0, 0,0,0, 1, 0, 1.f);
    // Vt = wv @ mem_n^T + bvi(per-row)   (1024 x 2048; small: keep 128^2)
    gemm_bt<1,2><<<dim3(16,8,1), 256, 0, stream>>>(inw_bf + 2097152, mem_n, in_b + 2048,
        Vt, 1024, 1024, 1024, 2048, 0,0,0, 0,0,0, 0,0,0, 1, 0, 1.f);

    for (int c0 = 0; c0 < 16; c0 += NC) {
        gemm256<256,1,0><<<dim3(8,8,NC), 512, 0, stream>>>(Qbuf, Kbuf, nullptr, scores,
            256, 1024, 1024, 2048,
            2097152, 256, 0,  0, 256, 0,  0, 0, 4194304, 4, c0, 0.0625f);
        softmax_rows<<<NC * 2048, 256, 0, stream>>>(scores);
        gemm256<128,1,0><<<dim3(2,8,NC), 512, 0, stream>>>(scores, Vt, nullptr, ctx,
            2048, 2048, 2048, 1024,
            0, 0, 4194304,  0, 524288, 0,  2097152, 256, 0, 4, c0, 1.f);
    }

    // attn_out -> cat[:, 1024:]
    gemm256<128,1,1><<<dim3(8,32,1), 512, 0, stream>>>(ctx, outw_bf, out_b,
        (void*)(cat + 1024), 1024, 1024, 1024, 2048, 0,0,0, 0,0,0, 0,0,0, 1, 0, 1.f);

    // gate = sigmoid(cat @ gate_w^T + gate_b) -> f32 in d_out
    gemm256<128,2,1><<<dim3(8,32,1), 512, 0, stream>>>(cat, gatew_bf, gate_b, gatev,
        2048, 2048, 2048, 1024, 0,0,0, 0,0,0, 0,0,0, 1, 0, 1.f);
    // h1 = cat @ int_w1^T + int_b1 (bf16, over dead q/Q)
    gemm256<256,1,1><<<dim3(8,32,1), 512, 0, stream>>>(cat, intw1_bf, int_b1, h1,
        2048, 2048, 2048, 2048, 0,0,0, 0,0,0, 0,0,0, 1, 0, 1.f);
    ln_gelu<<<NROWS, 256, 0, stream>>>(h1, int_ln_g, int_ln_b);
    // integ = h1 @ int_w2^T + int_b2 (bf16, over dead ctx)
    gemm256<128,1,1><<<dim3(8,32,1), 512, 0, stream>>>(h1, intw2_bf, int_b2, integ,
        2048, 2048, 2048, 1024, 0,0,0, 0,0,0, 0,0,0, 1, 0, 1.f);
    final_ln<<<NROWS, 256, 0, stream>>>(x, gatev, integ, ln2_g, ln2_b, (float*)d_out);
}

// Round 5
// 664.990 us; speedup vs baseline: 1.0744x; 1.0744x over previous
//
#include <hip/hip_runtime.h>

#define HDIM 1024
#define MMEM 8192
#define TOPK 2048
#define NROWS 8192
#define LNEPS 1e-5f

typedef unsigned short ushort_t;
typedef __bf16 bf16x8 __attribute__((ext_vector_type(8)));
typedef float f32x4 __attribute__((ext_vector_type(4)));
typedef __attribute__((address_space(1))) const void GVoid;
typedef __attribute__((address_space(3))) void LVoid;

// ---------- helpers ----------
__device__ __forceinline__ ushort_t f2bf(float f) {
    union { float f; unsigned u; } c; c.f = f;
    unsigned r = c.u + 0x7fffu + ((c.u >> 16) & 1u);
    return (ushort_t)(r >> 16);
}
__device__ __forceinline__ float bf2f(ushort_t u) {
    union { unsigned u; float f; } c; c.u = ((unsigned)u) << 16; return c.f;
}
__device__ __forceinline__ float blk_red(float v, int op, float* red) {
    #pragma unroll
    for (int o = 32; o; o >>= 1) {
        float u = __shfl_down(v, o);
        v = op ? fmaxf(v, u) : v + u;
    }
    if ((threadIdx.x & 63) == 0) red[threadIdx.x >> 6] = v;
    __syncthreads();
    float r = op ? fmaxf(fmaxf(red[0], red[1]), fmaxf(red[2], red[3]))
                 : (red[0] + red[1]) + (red[2] + red[3]);
    __syncthreads();
    return r;
}

// ---------- small prep kernels ----------
__global__ __launch_bounds__(256) void sel_prep(const float* __restrict__ sp,
        const float* __restrict__ imp, const float* __restrict__ rec,
        const float* __restrict__ ac, float* __restrict__ sel) {
    __shared__ float red[4];
    float p0 = sp[0], p1 = sp[1], p2 = sp[2];
    float mx = fmaxf(p0, fmaxf(p1, p2));
    float e0 = expf(p0 - mx), e1 = expf(p1 - mx), e2 = expf(p2 - mx);
    float inv = 1.f / (e0 + e1 + e2);
    float w0 = e0 * inv, w1 = e1 * inv, w2 = e2 * inv;
    float m = -1e30f;
    for (int i = threadIdx.x; i < MMEM; i += 256) m = fmaxf(m, ac[i]);
    m = blk_red(m, 1, red);
    float rinv = 1.f / m;
    for (int i = threadIdx.x; i < MMEM; i += 256)
        sel[i] = w0 * imp[i] + w1 * rec[i] + w2 * (ac[i] * rinv);
}

__global__ __launch_bounds__(256) void topk_rank(const float* __restrict__ sel,
                                                 int* __restrict__ idx) {
    __shared__ float s[MMEM];
    __shared__ int pc[256];
    for (int t = threadIdx.x; t < MMEM / 4; t += 256)
        reinterpret_cast<float4*>(s)[t] = reinterpret_cast<const float4*>(sel)[t];
    __syncthreads();
    const int li = threadIdx.x & 31;
    const int jc = threadIdx.x >> 5;
    const int i  = blockIdx.x * 32 + li;
    const float si = s[i];
    int cnt = 0;
    const float4* sv = reinterpret_cast<const float4*>(s) + jc * 256;
    #pragma unroll 4
    for (int t = 0; t < 256; ++t) {
        float4 v = sv[t];
        int j0 = jc * 1024 + t * 4;
        cnt += (v.x > si) || (v.x == si && (j0 + 0) < i);
        cnt += (v.y > si) || (v.y == si && (j0 + 1) < i);
        cnt += (v.z > si) || (v.z == si && (j0 + 2) < i);
        cnt += (v.w > si) || (v.w == si && (j0 + 3) < i);
    }
    pc[threadIdx.x] = cnt;
    __syncthreads();
    if (threadIdx.x < 32) {
        int r = 0;
        #pragma unroll
        for (int c = 0; c < 8; ++c) r += pc[c * 32 + threadIdx.x];
        if (r < TOPK) idx[r] = blockIdx.x * 32 + threadIdx.x;
    }
}

__global__ __launch_bounds__(256) void gather_ln(const float* __restrict__ mem_keys,
        const int* __restrict__ idx, const float* __restrict__ g,
        const float* __restrict__ b, ushort_t* __restrict__ out) {
    __shared__ float red[4];
    int src = idx[blockIdx.x] & (MMEM - 1);
    const float* x = mem_keys + (size_t)src * HDIM;
    float4 v = reinterpret_cast<const float4*>(x)[threadIdx.x];
    float s = v.x + v.y + v.z + v.w;
    float ss = v.x*v.x + v.y*v.y + v.z*v.z + v.w*v.w;
    s  = blk_red(s, 0, red);
    ss = blk_red(ss, 0, red);
    float mu = s * (1.f / HDIM);
    float var = ss * (1.f / HDIM) - mu * mu;
    float rstd = rsqrtf(var + LNEPS);
    int c = threadIdx.x * 4;
    ushort4 o;
    o.x = f2bf((v.x - mu) * rstd * g[c+0] + b[c+0]);
    o.y = f2bf((v.y - mu) * rstd * g[c+1] + b[c+1]);
    o.z = f2bf((v.z - mu) * rstd * g[c+2] + b[c+2]);
    o.w = f2bf((v.w - mu) * rstd * g[c+3] + b[c+3]);
    *reinterpret_cast<ushort4*>(out + (size_t)blockIdx.x * HDIM + c) = o;
}

__global__ __launch_bounds__(256) void cvt_bf16(const float* __restrict__ in,
                                                ushort_t* __restrict__ out) {
    size_t i = ((size_t)blockIdx.x * 256 + threadIdx.x) * 4;
    float4 v = *reinterpret_cast<const float4*>(in + i);
    ushort4 o = { f2bf(v.x), f2bf(v.y), f2bf(v.z), f2bf(v.w) };
    *reinterpret_cast<ushort4*>(out + i) = o;
}

__global__ __launch_bounds__(256) void cvt_x_cat(const float* __restrict__ x,
                                                 ushort_t* __restrict__ cat) {
    size_t i = ((size_t)blockIdx.x * 256 + threadIdx.x) * 4;
    size_t row = i >> 10, col = i & 1023;
    float4 v = *reinterpret_cast<const float4*>(x + i);
    ushort4 o = { f2bf(v.x), f2bf(v.y), f2bf(v.z), f2bf(v.w) };
    *reinterpret_cast<ushort4*>(cat + row * 2048 + col) = o;
}

__global__ __launch_bounds__(256) void softmax_rows(ushort_t* __restrict__ sc) {
    __shared__ float red[4];
    ushort_t* p = sc + (size_t)blockIdx.x * 2048 + threadIdx.x * 8;
    ushort4 a = reinterpret_cast<const ushort4*>(p)[0];
    ushort4 bq = reinterpret_cast<const ushort4*>(p)[1];
    float v[8] = { bf2f(a.x), bf2f(a.y), bf2f(a.z), bf2f(a.w),
                   bf2f(bq.x), bf2f(bq.y), bf2f(bq.z), bf2f(bq.w) };
    float mx = v[0];
    #pragma unroll
    for (int j = 1; j < 8; ++j) mx = fmaxf(mx, v[j]);
    mx = blk_red(mx, 1, red);
    float s = 0.f;
    #pragma unroll
    for (int j = 0; j < 8; ++j) { v[j] = expf(v[j] - mx); s += v[j]; }
    s = blk_red(s, 0, red);
    float inv = 1.f / s;
    ushort4 o1 = { f2bf(v[0]*inv), f2bf(v[1]*inv), f2bf(v[2]*inv), f2bf(v[3]*inv) };
    ushort4 o2 = { f2bf(v[4]*inv), f2bf(v[5]*inv), f2bf(v[6]*inv), f2bf(v[7]*inv) };
    reinterpret_cast<ushort4*>(p)[0] = o1;
    reinterpret_cast<ushort4*>(p)[1] = o2;
}

__global__ __launch_bounds__(256) void ln_gelu(ushort_t* h1,
        const float* __restrict__ g, const float* __restrict__ b) {
    __shared__ float red[4];
    ushort_t* p = h1 + (size_t)blockIdx.x * 2048 + threadIdx.x * 8;
    ushort4 a = reinterpret_cast<const ushort4*>(p)[0];
    ushort4 c = reinterpret_cast<const ushort4*>(p)[1];
    float v[8] = { bf2f(a.x), bf2f(a.y), bf2f(a.z), bf2f(a.w),
                   bf2f(c.x), bf2f(c.y), bf2f(c.z), bf2f(c.w) };
    float s = 0.f, ss = 0.f;
    #pragma unroll
    for (int j = 0; j < 8; ++j) { s += v[j]; ss += v[j]*v[j]; }
    s  = blk_red(s, 0, red);
    ss = blk_red(ss, 0, red);
    float mu = s * (1.f / 2048.f);
    float var = ss * (1.f / 2048.f) - mu * mu;
    float rstd = rsqrtf(var + LNEPS);
    int c0 = threadIdx.x * 8;
    ushort_t o[8];
    #pragma unroll
    for (int j = 0; j < 8; ++j) {
        float xn = (v[j] - mu) * rstd * g[c0 + j] + b[c0 + j];
        float ge = 0.5f * xn * (1.f + erff(xn * 0.70710678118654752f));
        o[j] = f2bf(ge);
    }
    ushort4 o1 = { o[0], o[1], o[2], o[3] };
    ushort4 o2 = { o[4], o[5], o[6], o[7] };
    reinterpret_cast<ushort4*>(p)[0] = o1;
    reinterpret_cast<ushort4*>(p)[1] = o2;
}

__global__ __launch_bounds__(256) void final_ln(const float* __restrict__ x,
        const float* gate, const ushort_t* __restrict__ integ,
        const float* __restrict__ g, const float* __restrict__ b,
        float* out) {
    __shared__ float red[4];
    size_t base = (size_t)blockIdx.x * HDIM + threadIdx.x * 4;
    float4 xv = *reinterpret_cast<const float4*>(x + base);
    float4 gv = *reinterpret_cast<const float4*>(gate + base);
    ushort4 iv = *reinterpret_cast<const ushort4*>(integ + base);
    float v[4] = { xv.x + gv.x*bf2f(iv.x), xv.y + gv.y*bf2f(iv.y),
                   xv.z + gv.z*bf2f(iv.z), xv.w + gv.w*bf2f(iv.w) };
    float s = v[0]+v[1]+v[2]+v[3];
    float ss = v[0]*v[0]+v[1]*v[1]+v[2]*v[2]+v[3]*v[3];
    s  = blk_red(s, 0, red);
    ss = blk_red(ss, 0, red);
    float mu = s * (1.f / HDIM);
    float var = ss * (1.f / HDIM) - mu * mu;
    float rstd = rsqrtf(var + LNEPS);
    int c = threadIdx.x * 4;
    float4 o;
    o.x = (v[0] - mu) * rstd * g[c+0] + b[c+0];
    o.y = (v[1] - mu) * rstd * g[c+1] + b[c+1];
    o.z = (v[2] - mu) * rstd * g[c+2] + b[c+2];
    o.w = (v[3] - mu) * rstd * g[c+3] + b[c+3];
    *reinterpret_cast<float4*>(out + base) = o;
}

// ---------- 128x128 MFMA GEMM (proven) ----------
template<int EPI, int BIAS>
__global__ __launch_bounds__(256, 2)
void gemm_bt(const ushort_t* __restrict__ A, const ushort_t* __restrict__ B,
             const float* __restrict__ bias, void* __restrict__ Cv,
             int K, int lda, int ldb, int ldc,
             long long sA1, long long sA2, long long sAz,
             long long sB1, long long sB2, long long sBz,
             long long sC1, long long sC2, long long sCz,
             int z2n, int zbase, float scale)
{
    __shared__ __align__(16) ushort_t As[8192];
    __shared__ __align__(16) ushort_t Bs[8192];
    const int zz = blockIdx.z;
    const int zg = zz + zbase;
    const int z1 = zg / z2n, z2 = zg - z1 * z2n;
    A += (size_t)(z1 * sA1 + z2 * sA2 + zz * sAz);
    B += (size_t)(z1 * sB1 + z2 * sB2 + zz * sBz);
    const size_t cOff = (size_t)(z1 * sC1 + z2 * sC2 + zz * sCz);
    const int m0 = blockIdx.y * 128, n0 = blockIdx.x * 128;
    const int tid = threadIdx.x;
    const int w = tid >> 6, l = tid & 63;
    const int wm = w >> 1, wn = w & 1;

    f32x4 acc[4][4] = {};
    const int srow = l >> 3;
    const int scol = ((l & 7) ^ srow) << 3;

    for (int k0 = 0; k0 < K; k0 += 64) {
        #pragma unroll
        for (int i = 0; i < 4; ++i) {
            const int c = i * 4 + w;
            const int row = c * 8 + srow;
            const ushort_t* ga = A + (size_t)(m0 + row) * lda + (k0 + scol);
            const ushort_t* gb = B + (size_t)(n0 + row) * ldb + (k0 + scol);
            __builtin_amdgcn_global_load_lds((GVoid*)ga, (LVoid*)(As + c * 512), 16, 0, 0);
            __builtin_amdgcn_global_load_lds((GVoid*)gb, (LVoid*)(Bs + c * 512), 16, 0, 0);
        }
        __syncthreads();
        #pragma unroll
        for (int kk = 0; kk < 2; ++kk) {
            bf16x8 af[4], bfv[4];
            #pragma unroll
            for (int m = 0; m < 4; ++m) {
                const int row = wm * 64 + m * 16 + (l & 15);
                const int cb = ((kk * 64) + ((l >> 4) * 16)) ^ ((row & 7) << 4);
                af[m] = *reinterpret_cast<const bf16x8*>(
                    reinterpret_cast<const char*>(As) + row * 128 + cb);
            }
            #pragma unroll
            for (int n = 0; n < 4; ++n) {
                const int row = wn * 64 + n * 16 + (l & 15);
                const int cb = ((kk * 64) + ((l >> 4) * 16)) ^ ((row & 7) << 4);
                bfv[n] = *reinterpret_cast<const bf16x8*>(
                    reinterpret_cast<const char*>(Bs) + row * 128 + cb);
            }
            #pragma unroll
            for (int m = 0; m < 4; ++m)
                #pragma unroll
                for (int n = 0; n < 4; ++n)
                    acc[m][n] = __builtin_amdgcn_mfma_f32_16x16x32_bf16(
                        af[m], bfv[n], acc[m][n], 0, 0, 0);
        }
        __syncthreads();
    }

    #pragma unroll
    for (int m = 0; m < 4; ++m) {
        const int grow = m0 + wm * 64 + m * 16 + ((l >> 4) << 2);
        #pragma unroll
        for (int n = 0; n < 4; ++n) {
            const int gcol = n0 + wn * 64 + n * 16 + (l & 15);
            float bc = (BIAS == 1) ? bias[gcol] : 0.f;
            #pragma unroll
            for (int j = 0; j < 4; ++j) {
                float v = acc[m][n][j] * scale;
                if (BIAS == 1) v += bc;
                if (BIAS == 2) v += bias[grow + j];
                if (EPI == 2) v = 1.f / (1.f + expf(-v));
                const size_t off = cOff + (size_t)(grow + j) * ldc + gcol;
                if (EPI == 1) ((ushort_t*)Cv)[off] = f2bf(v);
                else          ((float*)Cv)[off]    = v;
            }
        }
    }
}

// ---------- 256x256 8-phase GEMM (T3+T4+T5), grids multiple of 256 blocks ----
// waves 2M x 4N; per-wave out 128x64 interleaved: rows mq*128+wm*64+..,
// cols nq*128+wn*32+.. ; quadrant order per K-tile: (mq,nq)=(0,0),(1,0),(0,1),(1,1)
// staging: 1 half-tile (128 rows x 64 k, 2 loads/thread) per phase;
// vmcnt(6) at ph0/ph4 => 3 newest half-tiles in flight, tile resident.
#define SBAR8 asm volatile("s_barrier" ::: "memory")
#define VM6   asm volatile("s_waitcnt vmcnt(6)" ::: "memory")
#define VM0   asm volatile("s_waitcnt vmcnt(0)" ::: "memory")

#define STG8(P, ISB, H, T) do {                                               \
    const int k0_ = (T) << 6;                                                 \
    ushort_t* L_ = (ISB) ? &Bs[P][0] : &As[P][0];                             \
    const ushort_t* G_ = (ISB) ? B : A;                                       \
    const int ld_ = (ISB) ? ldb : lda;                                        \
    const int b0_ = (ISB) ? n0 : m0;                                          \
    _Pragma("unroll")                                                         \
    for (int j_ = 0; j_ < 2; ++j_) {                                          \
        const int c_ = j_ * 8 + wid;                                          \
        const int r_ = (H) * 128 + c_ * 8 + srow8;                            \
        const ushort_t* g_ = G_ + (size_t)(b0_ + r_) * ld_ + (k0_ + scol);    \
        __builtin_amdgcn_global_load_lds((GVoid*)g_,                          \
            (LVoid*)(L_ + ((H) * 16 + c_) * 512), 16, 0, 0);                  \
    }                                                                         \
} while (0)

#define COMP8(P, MQ, NQ) do {                                                 \
    const char* Ab_ = reinterpret_cast<const char*>(&As[P][0]);               \
    const char* Bb_ = reinterpret_cast<const char*>(&Bs[P][0]);               \
    bf16x8 af_[4][2], bf_[2][2];                                              \
    _Pragma("unroll")                                                         \
    for (int m_ = 0; m_ < 4; ++m_)                                            \
        _Pragma("unroll")                                                     \
        for (int kk_ = 0; kk_ < 2; ++kk_) {                                   \
            const int row_ = (MQ) * 128 + wm * 64 + m_ * 16 + (l & 15);       \
            const int cb_ = ((kk_ * 64) + ((l >> 4) * 16)) ^ ((row_ & 7) << 4); \
            af_[m_][kk_] = *reinterpret_cast<const bf16x8*>(Ab_ + row_ * 128 + cb_); \
        }                                                                     \
    _Pragma("unroll")                                                         \
    for (int n_ = 0; n_ < 2; ++n_)                                            \
        _Pragma("unroll")                                                     \
        for (int kk_ = 0; kk_ < 2; ++kk_) {                                   \
            const int col_ = (NQ) * 128 + wn * 32 + n_ * 16 + (l & 15);       \
            const int cb_ = ((kk_ * 64) + ((l >> 4) * 16)) ^ ((col_ & 7) << 4); \
            bf_[n_][kk_] = *reinterpret_cast<const bf16x8*>(Bb_ + col_ * 128 + cb_); \
        }                                                                     \
    __builtin_amdgcn_s_setprio(1);                                            \
    _Pragma("unroll")                                                         \
    for (int m_ = 0; m_ < 4; ++m_)                                            \
        _Pragma("unroll")                                                     \
        for (int n_ = 0; n_ < 2; ++n_)                                        \
            _Pragma("unroll")                                                 \
            for (int kk_ = 0; kk_ < 2; ++kk_)                                 \
                acc[(MQ)*4 + m_][(NQ)*2 + n_] =                               \
                    __builtin_amdgcn_mfma_f32_16x16x32_bf16(                  \
                        af_[m_][kk_], bf_[n_][kk_],                           \
                        acc[(MQ)*4 + m_][(NQ)*2 + n_], 0, 0, 0);              \
    __builtin_amdgcn_s_setprio(0);                                            \
} while (0)

template<int EPI, int BIAS>
__global__ __launch_bounds__(512, 2)
void gemm8p(const ushort_t* __restrict__ A, const ushort_t* __restrict__ B,
            const float* __restrict__ bias, void* __restrict__ Cv,
            int K, int lda, int ldb, int ldc,
            long long sA1, long long sA2, long long sBz2, long long sCz,
            int z2n, int zbase, float scale)
{
    __shared__ __align__(16) ushort_t As[2][16384];   // 2 x 256 x 64
    __shared__ __align__(16) ushort_t Bs[2][16384];   // 128 KiB total

    const int zz = blockIdx.z;
    const int zg = zz + zbase;
    const int z1 = zg / z2n, z2 = zg - z1 * z2n;
    A += (size_t)(z1 * sA1 + z2 * sA2);
    B += (size_t)(z2 * sBz2);
    const size_t cOff = (size_t)zz * sCz;

    const int m0 = blockIdx.y * 256, n0 = blockIdx.x * 256;
    const int tid = threadIdx.x;
    const int wid = tid >> 6, l = tid & 63;
    const int wm = wid >> 2, wn = wid & 3;          // 2M x 4N
    const int srow8 = l >> 3;
    const int scol  = ((l & 7) ^ srow8) << 3;

    f32x4 acc[8][4] = {};

    const int NT = K >> 6;                // even, >= 4
    const int jlast = (NT >> 1) - 1;

    // prologue: tile0 (4 halves -> buf0), tile1 A0/B0 (-> buf1)
    STG8(0, 0, 0, 0); STG8(0, 1, 0, 0);
    STG8(0, 0, 1, 0); STG8(0, 1, 1, 0);
    STG8(1, 0, 0, 1); STG8(1, 1, 0, 1);

    for (int j = 0; j <= jlast; ++j) {
        const int ta = 2 * j, tb = 2 * j + 1;
        // ph0: stage t(2j+1).B1 -> buf1 ; ensure tile 2j resident
        STG8(1, 1, 1, tb);
        VM6; SBAR8;
        COMP8(0, 0, 0); SBAR8;
        // ph1
        STG8(1, 0, 1, tb);
        COMP8(0, 1, 0); SBAR8;
        // ph2 (B-half0 of buf0 free after ph1)
        if (j < jlast) STG8(0, 1, 0, ta + 2);
        COMP8(0, 0, 1); SBAR8;
        // ph3 (A-half0 of buf0 free after ph2)
        if (j < jlast) STG8(0, 0, 0, ta + 2);
        COMP8(0, 1, 1); SBAR8;
        // ph4: ensure tile 2j+1 resident
        if (j < jlast) { STG8(0, 1, 1, ta + 2); VM6; }
        else          { VM0; }
        SBAR8;
        COMP8(1, 0, 0); SBAR8;
        // ph5
        if (j < jlast) STG8(0, 0, 1, ta + 2);
        COMP8(1, 1, 0); SBAR8;
        // ph6 (B-half0 of buf1 free after ph5)
        if (j < jlast) STG8(1, 1, 0, tb + 2);
        COMP8(1, 0, 1); SBAR8;
        // ph7 (A-half0 of buf1 free after ph6)
        if (j < jlast) STG8(1, 0, 0, tb + 2);
        COMP8(1, 1, 1); SBAR8;
    }

    #pragma unroll
    for (int mi = 0; mi < 8; ++mi) {
        const int grow = m0 + (mi >> 2) * 128 + wm * 64 + (mi & 3) * 16 + ((l >> 4) << 2);
        #pragma unroll
        for (int ni = 0; ni < 4; ++ni) {
            const int gcol = n0 + (ni >> 1) * 128 + wn * 32 + (ni & 1) * 16 + (l & 15);
            float bc = (BIAS == 1) ? bias[gcol] : 0.f;
            #pragma unroll
            for (int j = 0; j < 4; ++j) {
                float v = acc[mi][ni][j] * scale;
                if (BIAS == 1) v += bc;
                if (EPI == 2) v = 1.f / (1.f + expf(-v));
                const size_t off = cOff + (size_t)(grow + j) * ldc + gcol;
                if (EPI == 1) ((ushort_t*)Cv)[off] = f2bf(v);
                else          ((float*)Cv)[off]    = v;
            }
        }
    }
}

// ---------- host ----------
extern "C" void kernel_launch(void* const* d_in, const int* in_sizes, int n_in,
                              void* d_out, int out_size, void* d_ws, size_t ws_size,
                              hipStream_t stream) {
    const float* x          = (const float*)d_in[0];
    const float* mem_keys   = (const float*)d_in[1];
    const float* importance = (const float*)d_in[2];
    const float* recency    = (const float*)d_in[3];
    const float* access_cnt = (const float*)d_in[4];
    const float* Wq         = (const float*)d_in[5];
    const float* bq         = (const float*)d_in[6];
    const float* in_w       = (const float*)d_in[7];
    const float* in_b       = (const float*)d_in[8];
    const float* out_w      = (const float*)d_in[9];
    const float* out_b      = (const float*)d_in[10];
    const float* gate_w     = (const float*)d_in[11];
    const float* gate_b     = (const float*)d_in[12];
    const float* int_w1     = (const float*)d_in[13];
    const float* int_b1     = (const float*)d_in[14];
    const float* int_ln_g   = (const float*)d_in[15];
    const float* int_ln_b   = (const float*)d_in[16];
    const float* int_w2     = (const float*)d_in[17];
    const float* int_b2     = (const float*)d_in[18];
    const float* ln1_g      = (const float*)d_in[19];
    const float* ln1_b      = (const float*)d_in[20];
    const float* ln2_g      = (const float*)d_in[21];
    const float* ln2_b      = (const float*)d_in[22];
    const float* sel_params = (const float*)d_in[23];

    char* ws = (char*)d_ws;
    size_t off = 0;
    auto alloc = [&](size_t bytes) -> char* {
        char* p = ws + off;
        off = (off + bytes + 255) & ~(size_t)255;
        return p;
    };

    float*    sel      = (float*)alloc(MMEM * 4);
    int*      idx      = (int*)alloc(TOPK * 4);
    ushort_t* wq_bf    = (ushort_t*)alloc((size_t)1048576 * 2);
    ushort_t* inw_bf   = (ushort_t*)alloc((size_t)3145728 * 2);
    ushort_t* outw_bf  = (ushort_t*)alloc((size_t)1048576 * 2);
    ushort_t* gatew_bf = (ushort_t*)alloc((size_t)2097152 * 2);
    ushort_t* intw1_bf = (ushort_t*)alloc((size_t)4194304 * 2);
    ushort_t* intw2_bf = (ushort_t*)alloc((size_t)2097152 * 2);
    ushort_t* mem_n    = (ushort_t*)alloc((size_t)TOPK * HDIM * 2);
    ushort_t* Kbuf     = (ushort_t*)alloc((size_t)TOPK * HDIM * 2);
    ushort_t* Vt       = (ushort_t*)alloc((size_t)HDIM * TOPK * 2);
    ushort_t* cat      = (ushort_t*)alloc((size_t)NROWS * 2048 * 2);
    ushort_t* qQ       = (ushort_t*)alloc((size_t)NROWS * 2048 * 2);
    ushort_t* qbuf     = qQ;
    ushort_t* Qbuf     = qQ + (size_t)NROWS * HDIM;
    ushort_t* h1       = qQ;
    ushort_t* ctx      = (ushort_t*)alloc((size_t)NROWS * HDIM * 2);
    ushort_t* integ    = ctx;
    float*    gatev    = (float*)d_out;

    int NC = 8;
    while (NC > 1 && off + (size_t)NC * 8388608 > ws_size) NC >>= 1;
    ushort_t* scores = (ushort_t*)alloc((size_t)NC * 8388608);

    cvt_bf16<<<1024, 256, 0, stream>>>(Wq, wq_bf);
    cvt_bf16<<<3072, 256, 0, stream>>>(in_w, inw_bf);
    cvt_bf16<<<1024, 256, 0, stream>>>(out_w, outw_bf);
    cvt_bf16<<<2048, 256, 0, stream>>>(gate_w, gatew_bf);
    cvt_bf16<<<4096, 256, 0, stream>>>(int_w1, intw1_bf);
    cvt_bf16<<<2048, 256, 0, stream>>>(int_w2, intw2_bf);
    cvt_x_cat<<<8192, 256, 0, stream>>>(x, cat);

    sel_prep<<<1, 256, 0, stream>>>(sel_params, importance, recency, access_cnt, sel);
    topk_rank<<<MMEM/32, 256, 0, stream>>>(sel, idx);
    gather_ln<<<TOPK, 256, 0, stream>>>(mem_keys, idx, ln1_g, ln1_b, mem_n);

    // q = x @ Wq^T + bq
    gemm_bt<1,1><<<dim3(8,64,1), 256, 0, stream>>>(cat, wq_bf, bq, qbuf,
        1024, 2048, 1024, 1024, 0,0,0, 0,0,0, 0,0,0, 1, 0, 1.f);
    // Q = q @ wq^T + bqi
    gemm_bt<1,1><<<dim3(8,64,1), 256, 0, stream>>>(qbuf, inw_bf, in_b, Qbuf,
        1024, 1024, 1024, 1024, 0,0,0, 0,0,0, 0,0,0, 1, 0, 1.f);
    // K = mem_n @ wk^T + bki
    gemm_bt<1,1><<<dim3(8,16,1), 256, 0, stream>>>(mem_n, inw_bf + 1048576, in_b + 1024,
        Kbuf, 1024, 1024, 1024, 1024, 0,0,0, 0,0,0, 0,0,0, 1, 0, 1.f);
    // Vt = wv @ mem_n^T + bvi(per-row)
    gemm_bt<1,2><<<dim3(16,8,1), 256, 0, stream>>>(inw_bf + 2097152, mem_n, in_b + 2048,
        Vt, 1024, 1024, 1024, 2048, 0,0,0, 0,0,0, 0,0,0, 1, 0, 1.f);

    for (int c0 = 0; c0 < 16; c0 += NC) {
        // scores: 8-phase 256^2, grid 8x8xNC
        gemm8p<1,0><<<dim3(8,8,NC), 512, 0, stream>>>(Qbuf, Kbuf, nullptr, scores,
            256, 1024, 1024, 2048,
            /*sA1*/2097152, /*sA2*/256, /*sBz2*/256, /*sCz*/4194304, 4, c0, 0.0625f);
        softmax_rows<<<NC * 2048, 256, 0, stream>>>(scores);
        gemm_bt<1,0><<<dim3(2,16,NC), 256, 0, stream>>>(scores, Vt, nullptr, ctx,
            2048, 2048, 2048, 1024,
            0, 0, 4194304,  0, 524288, 0,  2097152, 256, 0, 4, c0, 1.f);
    }

    // attn_out -> cat[:, 1024:]
    gemm_bt<1,1><<<dim3(8,64,1), 256, 0, stream>>>(ctx, outw_bf, out_b,
        (void*)(cat + 1024), 1024, 1024, 1024, 2048, 0,0,0, 0,0,0, 0,0,0, 1, 0, 1.f);

    // gate = sigmoid(cat @ gate_w^T + gate_b) -> f32 in d_out
    gemm_bt<2,1><<<dim3(8,64,1), 256, 0, stream>>>(cat, gatew_bf, gate_b, gatev,
        2048, 2048, 2048, 1024, 0,0,0, 0,0,0, 0,0,0, 1, 0, 1.f);
    // h1 = cat @ int_w1^T + int_b1  (8-phase 256^2, grid 8x32 = 256 blocks)
    gemm8p<1,1><<<dim3(8,32,1), 512, 0, stream>>>(cat, intw1_bf, int_b1, h1,
        2048, 2048, 2048, 2048, 0,0,0,0, 1, 0, 1.f);
    ln_gelu<<<NROWS, 256, 0, stream>>>(h1, int_ln_g, int_ln_b);
    // integ = h1 @ int_w2^T + int_b2
    gemm_bt<1,1><<<dim3(8,64,1), 256, 0, stream>>>(h1, intw2_bf, int_b2, integ,
        2048, 2048, 2048, 1024, 0,0,0, 0,0,0, 0,0,0, 1, 0, 1.f);
    final_ln<<<NROWS, 256, 0, stream>>>(x, gatev, integ, ln2_g, ln2_b, (float*)d_out);
}

// Round 6
// 594.855 us; speedup vs baseline: 1.2010x; 1.1179x over previous
//
#include <hip/hip_runtime.h>

#define HDIM 1024
#define MMEM 8192
#define TOPK 2048
#define NROWS 8192
#define LNEPS 1e-5f

typedef unsigned short ushort_t;
typedef __bf16 bf16x8 __attribute__((ext_vector_type(8)));
typedef float f32x4 __attribute__((ext_vector_type(4)));
typedef __attribute__((address_space(1))) const void GVoid;
typedef __attribute__((address_space(3))) void LVoid;

// ---------- helpers ----------
__device__ __forceinline__ ushort_t f2bf(float f) {
    union { float f; unsigned u; } c; c.f = f;
    unsigned r = c.u + 0x7fffu + ((c.u >> 16) & 1u);
    return (ushort_t)(r >> 16);
}
__device__ __forceinline__ float bf2f(ushort_t u) {
    union { unsigned u; float f; } c; c.u = ((unsigned)u) << 16; return c.f;
}
__device__ __forceinline__ float blk_red(float v, int op, float* red) {
    #pragma unroll
    for (int o = 32; o; o >>= 1) {
        float u = __shfl_down(v, o);
        v = op ? fmaxf(v, u) : v + u;
    }
    if ((threadIdx.x & 63) == 0) red[threadIdx.x >> 6] = v;
    __syncthreads();
    float r = op ? fmaxf(fmaxf(red[0], red[1]), fmaxf(red[2], red[3]))
                 : (red[0] + red[1]) + (red[2] + red[3]);
    __syncthreads();
    return r;
}

// ---------- small prep kernels ----------
__global__ __launch_bounds__(256) void sel_prep(const float* __restrict__ sp,
        const float* __restrict__ imp, const float* __restrict__ rec,
        const float* __restrict__ ac, float* __restrict__ sel) {
    __shared__ float red[4];
    float p0 = sp[0], p1 = sp[1], p2 = sp[2];
    float mx = fmaxf(p0, fmaxf(p1, p2));
    float e0 = expf(p0 - mx), e1 = expf(p1 - mx), e2 = expf(p2 - mx);
    float inv = 1.f / (e0 + e1 + e2);
    float w0 = e0 * inv, w1 = e1 * inv, w2 = e2 * inv;
    float m = -1e30f;
    for (int i = threadIdx.x; i < MMEM; i += 256) m = fmaxf(m, ac[i]);
    m = blk_red(m, 1, red);
    float rinv = 1.f / m;
    for (int i = threadIdx.x; i < MMEM; i += 256)
        sel[i] = w0 * imp[i] + w1 * rec[i] + w2 * (ac[i] * rinv);
}

__global__ __launch_bounds__(256) void topk_rank(const float* __restrict__ sel,
                                                 int* __restrict__ idx) {
    __shared__ float s[MMEM];
    __shared__ int pc[256];
    for (int t = threadIdx.x; t < MMEM / 4; t += 256)
        reinterpret_cast<float4*>(s)[t] = reinterpret_cast<const float4*>(sel)[t];
    __syncthreads();
    const int li = threadIdx.x & 31;
    const int jc = threadIdx.x >> 5;
    const int i  = blockIdx.x * 32 + li;
    const float si = s[i];
    int cnt = 0;
    const float4* sv = reinterpret_cast<const float4*>(s) + jc * 256;
    #pragma unroll 4
    for (int t = 0; t < 256; ++t) {
        float4 v = sv[t];
        int j0 = jc * 1024 + t * 4;
        cnt += (v.x > si) || (v.x == si && (j0 + 0) < i);
        cnt += (v.y > si) || (v.y == si && (j0 + 1) < i);
        cnt += (v.z > si) || (v.z == si && (j0 + 2) < i);
        cnt += (v.w > si) || (v.w == si && (j0 + 3) < i);
    }
    pc[threadIdx.x] = cnt;
    __syncthreads();
    if (threadIdx.x < 32) {
        int r = 0;
        #pragma unroll
        for (int c = 0; c < 8; ++c) r += pc[c * 32 + threadIdx.x];
        if (r < TOPK) idx[r] = blockIdx.x * 32 + threadIdx.x;
    }
}

__global__ __launch_bounds__(256) void gather_ln(const float* __restrict__ mem_keys,
        const int* __restrict__ idx, const float* __restrict__ g,
        const float* __restrict__ b, ushort_t* __restrict__ out) {
    __shared__ float red[4];
    int src = idx[blockIdx.x] & (MMEM - 1);
    const float* x = mem_keys + (size_t)src * HDIM;
    float4 v = reinterpret_cast<const float4*>(x)[threadIdx.x];
    float s = v.x + v.y + v.z + v.w;
    float ss = v.x*v.x + v.y*v.y + v.z*v.z + v.w*v.w;
    s  = blk_red(s, 0, red);
    ss = blk_red(ss, 0, red);
    float mu = s * (1.f / HDIM);
    float var = ss * (1.f / HDIM) - mu * mu;
    float rstd = rsqrtf(var + LNEPS);
    int c = threadIdx.x * 4;
    ushort4 o;
    o.x = f2bf((v.x - mu) * rstd * g[c+0] + b[c+0]);
    o.y = f2bf((v.y - mu) * rstd * g[c+1] + b[c+1]);
    o.z = f2bf((v.z - mu) * rstd * g[c+2] + b[c+2]);
    o.w = f2bf((v.w - mu) * rstd * g[c+3] + b[c+3]);
    *reinterpret_cast<ushort4*>(out + (size_t)blockIdx.x * HDIM + c) = o;
}

__global__ __launch_bounds__(256) void cvt_bf16(const float* __restrict__ in,
                                                ushort_t* __restrict__ out) {
    size_t i = ((size_t)blockIdx.x * 256 + threadIdx.x) * 4;
    float4 v = *reinterpret_cast<const float4*>(in + i);
    ushort4 o = { f2bf(v.x), f2bf(v.y), f2bf(v.z), f2bf(v.w) };
    *reinterpret_cast<ushort4*>(out + i) = o;
}

// 1024x1024 f32 -> bf16 TRANSPOSED; grid (16,16): tile (by,bx) 64x64
__global__ __launch_bounds__(256) void cvt_t_bf16(const float* __restrict__ in,
                                                  ushort_t* __restrict__ out) {
    __shared__ ushort_t t[64][65];
    const int bx = blockIdx.x * 64, by = blockIdx.y * 64;
    const int r = threadIdx.x >> 4, c4 = (threadIdx.x & 15) << 2;
    #pragma unroll
    for (int rr = 0; rr < 64; rr += 16) {
        float4 v = *reinterpret_cast<const float4*>(in + (size_t)(by + r + rr) * 1024 + bx + c4);
        t[r + rr][c4 + 0] = f2bf(v.x);
        t[r + rr][c4 + 1] = f2bf(v.y);
        t[r + rr][c4 + 2] = f2bf(v.z);
        t[r + rr][c4 + 3] = f2bf(v.w);
    }
    __syncthreads();
    #pragma unroll
    for (int rr = 0; rr < 64; rr += 16) {
        const int i = r + rr;
        ushort4 o = { t[c4 + 0][i], t[c4 + 1][i], t[c4 + 2][i], t[c4 + 3][i] };
        *reinterpret_cast<ushort4*>(out + (size_t)(bx + i) * 1024 + by + c4) = o;
    }
}

// beff[n] = dot(wq[n,:], bq) + bqi[n]; grid 1024
__global__ __launch_bounds__(256) void bias_fold(const float* __restrict__ wq,
        const float* __restrict__ bq, const float* __restrict__ bqi,
        float* __restrict__ beff) {
    __shared__ float red[4];
    const float4 wv = reinterpret_cast<const float4*>(wq + (size_t)blockIdx.x * 1024)[threadIdx.x];
    const float4 bv = reinterpret_cast<const float4*>(bq)[threadIdx.x];
    float s = wv.x*bv.x + wv.y*bv.y + wv.z*bv.z + wv.w*bv.w;
    s = blk_red(s, 0, red);
    if (threadIdx.x == 0) beff[blockIdx.x] = s + bqi[blockIdx.x];
}

__global__ __launch_bounds__(256) void cvt_x_cat(const float* __restrict__ x,
                                                 ushort_t* __restrict__ cat) {
    size_t i = ((size_t)blockIdx.x * 256 + threadIdx.x) * 4;
    size_t row = i >> 10, col = i & 1023;
    float4 v = *reinterpret_cast<const float4*>(x + i);
    ushort4 o = { f2bf(v.x), f2bf(v.y), f2bf(v.z), f2bf(v.w) };
    *reinterpret_cast<ushort4*>(cat + row * 2048 + col) = o;
}

__global__ __launch_bounds__(256) void softmax_rows(ushort_t* __restrict__ sc) {
    __shared__ float red[4];
    ushort_t* p = sc + (size_t)blockIdx.x * 2048 + threadIdx.x * 8;
    ushort4 a = reinterpret_cast<const ushort4*>(p)[0];
    ushort4 bq = reinterpret_cast<const ushort4*>(p)[1];
    float v[8] = { bf2f(a.x), bf2f(a.y), bf2f(a.z), bf2f(a.w),
                   bf2f(bq.x), bf2f(bq.y), bf2f(bq.z), bf2f(bq.w) };
    float mx = v[0];
    #pragma unroll
    for (int j = 1; j < 8; ++j) mx = fmaxf(mx, v[j]);
    mx = blk_red(mx, 1, red);
    float s = 0.f;
    #pragma unroll
    for (int j = 0; j < 8; ++j) { v[j] = expf(v[j] - mx); s += v[j]; }
    s = blk_red(s, 0, red);
    float inv = 1.f / s;
    ushort4 o1 = { f2bf(v[0]*inv), f2bf(v[1]*inv), f2bf(v[2]*inv), f2bf(v[3]*inv) };
    ushort4 o2 = { f2bf(v[4]*inv), f2bf(v[5]*inv), f2bf(v[6]*inv), f2bf(v[7]*inv) };
    reinterpret_cast<ushort4*>(p)[0] = o1;
    reinterpret_cast<ushort4*>(p)[1] = o2;
}

__global__ __launch_bounds__(256) void ln_gelu(ushort_t* h1,
        const float* __restrict__ g, const float* __restrict__ b) {
    __shared__ float red[4];
    ushort_t* p = h1 + (size_t)blockIdx.x * 2048 + threadIdx.x * 8;
    ushort4 a = reinterpret_cast<const ushort4*>(p)[0];
    ushort4 c = reinterpret_cast<const ushort4*>(p)[1];
    float v[8] = { bf2f(a.x), bf2f(a.y), bf2f(a.z), bf2f(a.w),
                   bf2f(c.x), bf2f(c.y), bf2f(c.z), bf2f(c.w) };
    float s = 0.f, ss = 0.f;
    #pragma unroll
    for (int j = 0; j < 8; ++j) { s += v[j]; ss += v[j]*v[j]; }
    s  = blk_red(s, 0, red);
    ss = blk_red(ss, 0, red);
    float mu = s * (1.f / 2048.f);
    float var = ss * (1.f / 2048.f) - mu * mu;
    float rstd = rsqrtf(var + LNEPS);
    int c0 = threadIdx.x * 8;
    ushort_t o[8];
    #pragma unroll
    for (int j = 0; j < 8; ++j) {
        float xn = (v[j] - mu) * rstd * g[c0 + j] + b[c0 + j];
        float ge = 0.5f * xn * (1.f + erff(xn * 0.70710678118654752f));
        o[j] = f2bf(ge);
    }
    ushort4 o1 = { o[0], o[1], o[2], o[3] };
    ushort4 o2 = { o[4], o[5], o[6], o[7] };
    reinterpret_cast<ushort4*>(p)[0] = o1;
    reinterpret_cast<ushort4*>(p)[1] = o2;
}

__global__ __launch_bounds__(256) void final_ln(const float* __restrict__ x,
        const float* gate, const ushort_t* __restrict__ integ,
        const float* __restrict__ g, const float* __restrict__ b,
        float* out) {
    __shared__ float red[4];
    size_t base = (size_t)blockIdx.x * HDIM + threadIdx.x * 4;
    float4 xv = *reinterpret_cast<const float4*>(x + base);
    float4 gv = *reinterpret_cast<const float4*>(gate + base);
    ushort4 iv = *reinterpret_cast<const ushort4*>(integ + base);
    float v[4] = { xv.x + gv.x*bf2f(iv.x), xv.y + gv.y*bf2f(iv.y),
                   xv.z + gv.z*bf2f(iv.z), xv.w + gv.w*bf2f(iv.w) };
    float s = v[0]+v[1]+v[2]+v[3];
    float ss = v[0]*v[0]+v[1]*v[1]+v[2]*v[2]+v[3]*v[3];
    s  = blk_red(s, 0, red);
    ss = blk_red(ss, 0, red);
    float mu = s * (1.f / HDIM);
    float var = ss * (1.f / HDIM) - mu * mu;
    float rstd = rsqrtf(var + LNEPS);
    int c = threadIdx.x * 4;
    float4 o;
    o.x = (v[0] - mu) * rstd * g[c+0] + b[c+0];
    o.y = (v[1] - mu) * rstd * g[c+1] + b[c+1];
    o.z = (v[2] - mu) * rstd * g[c+2] + b[c+2];
    o.w = (v[3] - mu) * rstd * g[c+3] + b[c+3];
    *reinterpret_cast<float4*>(out + base) = o;
}

// ---------- 128x128 MFMA GEMM (proven) + T1 XCD swizzle ----------
template<int EPI, int BIAS>
__global__ __launch_bounds__(256, 2)
void gemm_bt(const ushort_t* __restrict__ A, const ushort_t* __restrict__ B,
             const float* __restrict__ bias, void* __restrict__ Cv,
             int K, int lda, int ldb, int ldc,
             long long sA1, long long sA2, long long sAz,
             long long sB1, long long sB2, long long sBz,
             long long sC1, long long sC2, long long sCz,
             int z2n, int zbase, float scale)
{
    __shared__ __align__(16) ushort_t As[8192];
    __shared__ __align__(16) ushort_t Bs[8192];
    const int zz = blockIdx.z;
    const int zg = zz + zbase;
    const int z1 = zg / z2n, z2 = zg - z1 * z2n;
    A += (size_t)(z1 * sA1 + z2 * sA2 + zz * sAz);
    B += (size_t)(z1 * sB1 + z2 * sB2 + zz * sBz);
    const size_t cOff = (size_t)(z1 * sC1 + z2 * sC2 + zz * sCz);

    // bijective XCD swizzle (m204): contiguous tile chunk per XCD
    const int nwg = gridDim.x * gridDim.y;
    const int wg  = blockIdx.y * gridDim.x + blockIdx.x;
    const int q8  = nwg >> 3, r8 = nwg & 7;
    const int xcd = wg & 7, lo = wg >> 3;
    const int wgid = (xcd < r8 ? xcd * (q8 + 1) : r8 * (q8 + 1) + (xcd - r8) * q8) + lo;
    const int m0 = (wgid / gridDim.x) * 128, n0 = (wgid % gridDim.x) * 128;

    const int tid = threadIdx.x;
    const int w = tid >> 6, l = tid & 63;
    const int wm = w >> 1, wn = w & 1;

    f32x4 acc[4][4] = {};
    const int srow = l >> 3;
    const int scol = ((l & 7) ^ srow) << 3;

    for (int k0 = 0; k0 < K; k0 += 64) {
        #pragma unroll
        for (int i = 0; i < 4; ++i) {
            const int c = i * 4 + w;
            const int row = c * 8 + srow;
            const ushort_t* ga = A + (size_t)(m0 + row) * lda + (k0 + scol);
            const ushort_t* gb = B + (size_t)(n0 + row) * ldb + (k0 + scol);
            __builtin_amdgcn_global_load_lds((GVoid*)ga, (LVoid*)(As + c * 512), 16, 0, 0);
            __builtin_amdgcn_global_load_lds((GVoid*)gb, (LVoid*)(Bs + c * 512), 16, 0, 0);
        }
        __syncthreads();
        #pragma unroll
        for (int kk = 0; kk < 2; ++kk) {
            bf16x8 af[4], bfv[4];
            #pragma unroll
            for (int m = 0; m < 4; ++m) {
                const int row = wm * 64 + m * 16 + (l & 15);
                const int cb = ((kk * 64) + ((l >> 4) * 16)) ^ ((row & 7) << 4);
                af[m] = *reinterpret_cast<const bf16x8*>(
                    reinterpret_cast<const char*>(As) + row * 128 + cb);
            }
            #pragma unroll
            for (int n = 0; n < 4; ++n) {
                const int row = wn * 64 + n * 16 + (l & 15);
                const int cb = ((kk * 64) + ((l >> 4) * 16)) ^ ((row & 7) << 4);
                bfv[n] = *reinterpret_cast<const bf16x8*>(
                    reinterpret_cast<const char*>(Bs) + row * 128 + cb);
            }
            #pragma unroll
            for (int m = 0; m < 4; ++m)
                #pragma unroll
                for (int n = 0; n < 4; ++n)
                    acc[m][n] = __builtin_amdgcn_mfma_f32_16x16x32_bf16(
                        af[m], bfv[n], acc[m][n], 0, 0, 0);
        }
        __syncthreads();
    }

    #pragma unroll
    for (int m = 0; m < 4; ++m) {
        const int grow = m0 + wm * 64 + m * 16 + ((l >> 4) << 2);
        #pragma unroll
        for (int n = 0; n < 4; ++n) {
            const int gcol = n0 + wn * 64 + n * 16 + (l & 15);
            float bc = (BIAS == 1) ? bias[gcol] : 0.f;
            #pragma unroll
            for (int j = 0; j < 4; ++j) {
                float v = acc[m][n][j] * scale;
                if (BIAS == 1) v += bc;
                if (BIAS == 2) v += bias[grow + j];
                if (EPI == 2) v = 1.f / (1.f + expf(-v));
                const size_t off = cOff + (size_t)(grow + j) * ldc + gcol;
                if (EPI == 1) ((ushort_t*)Cv)[off] = f2bf(v);
                else          ((float*)Cv)[off]    = v;
            }
        }
    }
}

// ---------- host ----------
extern "C" void kernel_launch(void* const* d_in, const int* in_sizes, int n_in,
                              void* d_out, int out_size, void* d_ws, size_t ws_size,
                              hipStream_t stream) {
    const float* x          = (const float*)d_in[0];
    const float* mem_keys   = (const float*)d_in[1];
    const float* importance = (const float*)d_in[2];
    const float* recency    = (const float*)d_in[3];
    const float* access_cnt = (const float*)d_in[4];
    const float* Wq         = (const float*)d_in[5];
    const float* bq         = (const float*)d_in[6];
    const float* in_w       = (const float*)d_in[7];
    const float* in_b       = (const float*)d_in[8];
    const float* out_w      = (const float*)d_in[9];
    const float* out_b      = (const float*)d_in[10];
    const float* gate_w     = (const float*)d_in[11];
    const float* gate_b     = (const float*)d_in[12];
    const float* int_w1     = (const float*)d_in[13];
    const float* int_b1     = (const float*)d_in[14];
    const float* int_ln_g   = (const float*)d_in[15];
    const float* int_ln_b   = (const float*)d_in[16];
    const float* int_w2     = (const float*)d_in[17];
    const float* int_b2     = (const float*)d_in[18];
    const float* ln1_g      = (const float*)d_in[19];
    const float* ln1_b      = (const float*)d_in[20];
    const float* ln2_g      = (const float*)d_in[21];
    const float* ln2_b      = (const float*)d_in[22];
    const float* sel_params = (const float*)d_in[23];

    char* ws = (char*)d_ws;
    size_t off = 0;
    auto alloc = [&](size_t bytes) -> char* {
        char* p = ws + off;
        off = (off + bytes + 255) & ~(size_t)255;
        return p;
    };

    float*    sel      = (float*)alloc(MMEM * 4);
    int*      idx      = (int*)alloc(TOPK * 4);
    float*    beff     = (float*)alloc(1024 * 4);
    ushort_t* wqT_bf   = (ushort_t*)alloc((size_t)1048576 * 2);   // Wq^T bf16
    ushort_t* weff_bf  = (ushort_t*)alloc((size_t)1048576 * 2);   // wq @ Wq bf16
    ushort_t* inw_bf   = (ushort_t*)alloc((size_t)3145728 * 2);
    ushort_t* outw_bf  = (ushort_t*)alloc((size_t)1048576 * 2);
    ushort_t* gatew_bf = (ushort_t*)alloc((size_t)2097152 * 2);
    ushort_t* intw1_bf = (ushort_t*)alloc((size_t)4194304 * 2);
    ushort_t* intw2_bf = (ushort_t*)alloc((size_t)2097152 * 2);
    ushort_t* mem_n    = (ushort_t*)alloc((size_t)TOPK * HDIM * 2);
    ushort_t* Kbuf     = (ushort_t*)alloc((size_t)TOPK * HDIM * 2);
    ushort_t* Vt       = (ushort_t*)alloc((size_t)HDIM * TOPK * 2);
    ushort_t* cat      = (ushort_t*)alloc((size_t)NROWS * 2048 * 2);
    ushort_t* qQ       = (ushort_t*)alloc((size_t)NROWS * 2048 * 2);
    ushort_t* Qbuf     = qQ + (size_t)NROWS * HDIM;     // second half
    ushort_t* h1       = qQ;                            // Q dead by h1 time
    ushort_t* ctx      = (ushort_t*)alloc((size_t)NROWS * HDIM * 2);
    ushort_t* integ    = ctx;
    float*    gatev    = (float*)d_out;

    int NC = 8;
    while (NC > 1 && off + (size_t)NC * 8388608 > ws_size) NC >>= 1;
    ushort_t* scores = (ushort_t*)alloc((size_t)NC * 8388608);

    // weight conversions
    cvt_t_bf16<<<dim3(16,16), 256, 0, stream>>>(Wq, wqT_bf);
    cvt_bf16<<<3072, 256, 0, stream>>>(in_w, inw_bf);
    cvt_bf16<<<1024, 256, 0, stream>>>(out_w, outw_bf);
    cvt_bf16<<<2048, 256, 0, stream>>>(gate_w, gatew_bf);
    cvt_bf16<<<4096, 256, 0, stream>>>(int_w1, intw1_bf);
    cvt_bf16<<<2048, 256, 0, stream>>>(int_w2, intw2_bf);
    cvt_x_cat<<<8192, 256, 0, stream>>>(x, cat);
    bias_fold<<<1024, 256, 0, stream>>>(in_w, bq, in_b, beff);

    // W_eff = wq . (Wq^T)^T  (1024x1024, bf16)
    gemm_bt<1,0><<<dim3(8,8,1), 256, 0, stream>>>(inw_bf, wqT_bf, nullptr, weff_bf,
        1024, 1024, 1024, 1024, 0,0,0, 0,0,0, 0,0,0, 1, 0, 1.f);

    sel_prep<<<1, 256, 0, stream>>>(sel_params, importance, recency, access_cnt, sel);
    topk_rank<<<MMEM/32, 256, 0, stream>>>(sel, idx);
    gather_ln<<<TOPK, 256, 0, stream>>>(mem_keys, idx, ln1_g, ln1_b, mem_n);

    // Q = x @ W_eff^T + beff   (folded q-projection)
    gemm_bt<1,1><<<dim3(8,64,1), 256, 0, stream>>>(cat, weff_bf, beff, Qbuf,
        1024, 2048, 1024, 1024, 0,0,0, 0,0,0, 0,0,0, 1, 0, 1.f);
    // K = mem_n @ wk^T + bki
    gemm_bt<1,1><<<dim3(8,16,1), 256, 0, stream>>>(mem_n, inw_bf + 1048576, in_b + 1024,
        Kbuf, 1024, 1024, 1024, 1024, 0,0,0, 0,0,0, 0,0,0, 1, 0, 1.f);
    // Vt = wv @ mem_n^T + bvi(per-row)
    gemm_bt<1,2><<<dim3(16,8,1), 256, 0, stream>>>(inw_bf + 2097152, mem_n, in_b + 2048,
        Vt, 1024, 1024, 1024, 2048, 0,0,0, 0,0,0, 0,0,0, 1, 0, 1.f);

    for (int c0 = 0; c0 < 16; c0 += NC) {
        gemm_bt<1,0><<<dim3(16,16,NC), 256, 0, stream>>>(Qbuf, Kbuf, nullptr, scores,
            256, 1024, 1024, 2048,
            2097152, 256, 0,  0, 256, 0,  0, 0, 4194304, 4, c0, 0.0625f);
        softmax_rows<<<NC * 2048, 256, 0, stream>>>(scores);
        gemm_bt<1,0><<<dim3(2,16,NC), 256, 0, stream>>>(scores, Vt, nullptr, ctx,
            2048, 2048, 2048, 1024,
            0, 0, 4194304,  0, 524288, 0,  2097152, 256, 0, 4, c0, 1.f);
    }

    // attn_out -> cat[:, 1024:]
    gemm_bt<1,1><<<dim3(8,64,1), 256, 0, stream>>>(ctx, outw_bf, out_b,
        (void*)(cat + 1024), 1024, 1024, 1024, 2048, 0,0,0, 0,0,0, 0,0,0, 1, 0, 1.f);

    // gate = sigmoid(cat @ gate_w^T + gate_b) -> f32 in d_out
    gemm_bt<2,1><<<dim3(8,64,1), 256, 0, stream>>>(cat, gatew_bf, gate_b, gatev,
        2048, 2048, 2048, 1024, 0,0,0, 0,0,0, 0,0,0, 1, 0, 1.f);
    // h1 = cat @ int_w1^T + int_b1
    gemm_bt<1,1><<<dim3(16,64,1), 256, 0, stream>>>(cat, intw1_bf, int_b1, h1,
        2048, 2048, 2048, 2048, 0,0,0, 0,0,0, 0,0,0, 1, 0, 1.f);
    ln_gelu<<<NROWS, 256, 0, stream>>>(h1, int_ln_g, int_ln_b);
    // integ = h1 @ int_w2^T + int_b2
    gemm_bt<1,1><<<dim3(8,64,1), 256, 0, stream>>>(h1, intw2_bf, int_b2, integ,
        2048, 2048, 2048, 1024, 0,0,0, 0,0,0, 0,0,0, 1, 0, 1.f);
    final_ln<<<NROWS, 256, 0, stream>>>(x, gatev, integ, ln2_g, ln2_b, (float*)d_out);
}

// Round 7
// 584.110 us; speedup vs baseline: 1.2231x; 1.0184x over previous
//
#include <hip/hip_runtime.h>

#define HDIM 1024
#define MMEM 8192
#define TOPK 2048
#define NROWS 8192
#define LNEPS 1e-5f

typedef unsigned short ushort_t;
typedef __bf16 bf16x8 __attribute__((ext_vector_type(8)));
typedef float f32x4 __attribute__((ext_vector_type(4)));
typedef __attribute__((address_space(1))) const void GVoid;
typedef __attribute__((address_space(3))) void LVoid;

// ---------- helpers ----------
__device__ __forceinline__ ushort_t f2bf(float f) {
    union { float f; unsigned u; } c; c.f = f;
    unsigned r = c.u + 0x7fffu + ((c.u >> 16) & 1u);
    return (ushort_t)(r >> 16);
}
__device__ __forceinline__ float bf2f(ushort_t u) {
    union { unsigned u; float f; } c; c.u = ((unsigned)u) << 16; return c.f;
}
__device__ __forceinline__ float blk_red(float v, int op, float* red) {
    #pragma unroll
    for (int o = 32; o; o >>= 1) {
        float u = __shfl_down(v, o);
        v = op ? fmaxf(v, u) : v + u;
    }
    if ((threadIdx.x & 63) == 0) red[threadIdx.x >> 6] = v;
    __syncthreads();
    float r = op ? fmaxf(fmaxf(red[0], red[1]), fmaxf(red[2], red[3]))
                 : (red[0] + red[1]) + (red[2] + red[3]);
    __syncthreads();
    return r;
}

// ---------- small prep kernels ----------
__global__ __launch_bounds__(256) void sel_prep(const float* __restrict__ sp,
        const float* __restrict__ imp, const float* __restrict__ rec,
        const float* __restrict__ ac, float* __restrict__ sel) {
    __shared__ float red[4];
    float p0 = sp[0], p1 = sp[1], p2 = sp[2];
    float mx = fmaxf(p0, fmaxf(p1, p2));
    float e0 = expf(p0 - mx), e1 = expf(p1 - mx), e2 = expf(p2 - mx);
    float inv = 1.f / (e0 + e1 + e2);
    float w0 = e0 * inv, w1 = e1 * inv, w2 = e2 * inv;
    float m = -1e30f;
    for (int i = threadIdx.x; i < MMEM; i += 256) m = fmaxf(m, ac[i]);
    m = blk_red(m, 1, red);
    float rinv = 1.f / m;
    for (int i = threadIdx.x; i < MMEM; i += 256)
        sel[i] = w0 * imp[i] + w1 * rec[i] + w2 * (ac[i] * rinv);
}

__global__ __launch_bounds__(256) void topk_rank(const float* __restrict__ sel,
                                                 int* __restrict__ idx) {
    __shared__ float s[MMEM];
    __shared__ int pc[256];
    for (int t = threadIdx.x; t < MMEM / 4; t += 256)
        reinterpret_cast<float4*>(s)[t] = reinterpret_cast<const float4*>(sel)[t];
    __syncthreads();
    const int li = threadIdx.x & 31;
    const int jc = threadIdx.x >> 5;
    const int i  = blockIdx.x * 32 + li;
    const float si = s[i];
    int cnt = 0;
    const float4* sv = reinterpret_cast<const float4*>(s) + jc * 256;
    #pragma unroll 4
    for (int t = 0; t < 256; ++t) {
        float4 v = sv[t];
        int j0 = jc * 1024 + t * 4;
        cnt += (v.x > si) || (v.x == si && (j0 + 0) < i);
        cnt += (v.y > si) || (v.y == si && (j0 + 1) < i);
        cnt += (v.z > si) || (v.z == si && (j0 + 2) < i);
        cnt += (v.w > si) || (v.w == si && (j0 + 3) < i);
    }
    pc[threadIdx.x] = cnt;
    __syncthreads();
    if (threadIdx.x < 32) {
        int r = 0;
        #pragma unroll
        for (int c = 0; c < 8; ++c) r += pc[c * 32 + threadIdx.x];
        if (r < TOPK) idx[r] = blockIdx.x * 32 + threadIdx.x;
    }
}

__global__ __launch_bounds__(256) void gather_ln(const float* __restrict__ mem_keys,
        const int* __restrict__ idx, const float* __restrict__ g,
        const float* __restrict__ b, ushort_t* __restrict__ out) {
    __shared__ float red[4];
    int src = idx[blockIdx.x] & (MMEM - 1);
    const float* x = mem_keys + (size_t)src * HDIM;
    float4 v = reinterpret_cast<const float4*>(x)[threadIdx.x];
    float s = v.x + v.y + v.z + v.w;
    float ss = v.x*v.x + v.y*v.y + v.z*v.z + v.w*v.w;
    s  = blk_red(s, 0, red);
    ss = blk_red(ss, 0, red);
    float mu = s * (1.f / HDIM);
    float var = ss * (1.f / HDIM) - mu * mu;
    float rstd = rsqrtf(var + LNEPS);
    int c = threadIdx.x * 4;
    ushort4 o;
    o.x = f2bf((v.x - mu) * rstd * g[c+0] + b[c+0]);
    o.y = f2bf((v.y - mu) * rstd * g[c+1] + b[c+1]);
    o.z = f2bf((v.z - mu) * rstd * g[c+2] + b[c+2]);
    o.w = f2bf((v.w - mu) * rstd * g[c+3] + b[c+3]);
    *reinterpret_cast<ushort4*>(out + (size_t)blockIdx.x * HDIM + c) = o;
}

// merged f32->bf16 weight conversion: in_w, out_w, gate_w->gw3[0:], int_w1->gw3[1024*2048:], int_w2
__global__ __launch_bounds__(256) void cvt_all(const float* __restrict__ in_w,
        const float* __restrict__ out_w, const float* __restrict__ gate_w,
        const float* __restrict__ int_w1, const float* __restrict__ int_w2,
        ushort_t* __restrict__ inw_bf, ushort_t* __restrict__ outw_bf,
        ushort_t* __restrict__ gw3, ushort_t* __restrict__ intw2_bf) {
    const int b = blockIdx.x;
    const float* src; ushort_t* dst; int rel;
    if      (b < 3072)  { src = in_w;   dst = inw_bf;        rel = b; }
    else if (b < 4096)  { src = out_w;  dst = outw_bf;       rel = b - 3072; }
    else if (b < 6144)  { src = gate_w; dst = gw3;           rel = b - 4096; }
    else if (b < 10240) { src = int_w1; dst = gw3 + 2097152; rel = b - 6144; }
    else                { src = int_w2; dst = intw2_bf;      rel = b - 10240; }
    size_t i = ((size_t)rel * 256 + threadIdx.x) * 4;
    float4 v = *reinterpret_cast<const float4*>(src + i);
    ushort4 o = { f2bf(v.x), f2bf(v.y), f2bf(v.z), f2bf(v.w) };
    *reinterpret_cast<ushort4*>(dst + i) = o;
}

// 1024x1024 f32 -> bf16 TRANSPOSED
__global__ __launch_bounds__(256) void cvt_t_bf16(const float* __restrict__ in,
                                                  ushort_t* __restrict__ out) {
    __shared__ ushort_t t[64][65];
    const int bx = blockIdx.x * 64, by = blockIdx.y * 64;
    const int r = threadIdx.x >> 4, c4 = (threadIdx.x & 15) << 2;
    #pragma unroll
    for (int rr = 0; rr < 64; rr += 16) {
        float4 v = *reinterpret_cast<const float4*>(in + (size_t)(by + r + rr) * 1024 + bx + c4);
        t[r + rr][c4 + 0] = f2bf(v.x);
        t[r + rr][c4 + 1] = f2bf(v.y);
        t[r + rr][c4 + 2] = f2bf(v.z);
        t[r + rr][c4 + 3] = f2bf(v.w);
    }
    __syncthreads();
    #pragma unroll
    for (int rr = 0; rr < 64; rr += 16) {
        const int i = r + rr;
        ushort4 o = { t[c4 + 0][i], t[c4 + 1][i], t[c4 + 2][i], t[c4 + 3][i] };
        *reinterpret_cast<ushort4*>(out + (size_t)(bx + i) * 1024 + by + c4) = o;
    }
}

// beff[n] = dot(wq[n,:], bq) + bqi[n]
__global__ __launch_bounds__(256) void bias_fold(const float* __restrict__ wq,
        const float* __restrict__ bq, const float* __restrict__ bqi,
        float* __restrict__ beff) {
    __shared__ float red[4];
    const float4 wv = reinterpret_cast<const float4*>(wq + (size_t)blockIdx.x * 1024)[threadIdx.x];
    const float4 bv = reinterpret_cast<const float4*>(bq)[threadIdx.x];
    float s = wv.x*bv.x + wv.y*bv.y + wv.z*bv.z + wv.w*bv.w;
    s = blk_red(s, 0, red);
    if (threadIdx.x == 0) beff[blockIdx.x] = s + bqi[blockIdx.x];
}

__global__ __launch_bounds__(256) void cvt_x_cat(const float* __restrict__ x,
                                                 ushort_t* __restrict__ cat) {
    size_t i = ((size_t)blockIdx.x * 256 + threadIdx.x) * 4;
    size_t row = i >> 10, col = i & 1023;
    float4 v = *reinterpret_cast<const float4*>(x + i);
    ushort4 o = { f2bf(v.x), f2bf(v.y), f2bf(v.z), f2bf(v.w) };
    *reinterpret_cast<ushort4*>(cat + row * 2048 + col) = o;
}

// wave-per-row softmax over 2048 bf16; grid = nrows/4, 256 threads
__global__ __launch_bounds__(256) void softmax_rows(ushort_t* __restrict__ sc) {
    const int row = blockIdx.x * 4 + (threadIdx.x >> 6);
    const int l = threadIdx.x & 63;
    uint4* p = reinterpret_cast<uint4*>(sc + (size_t)row * 2048 + l * 32);
    uint4 u[4];
    #pragma unroll
    for (int i = 0; i < 4; ++i) u[i] = p[i];
    float v[32];
    #pragma unroll
    for (int i = 0; i < 4; ++i) {
        unsigned* w = reinterpret_cast<unsigned*>(&u[i]);
        #pragma unroll
        for (int k = 0; k < 4; ++k) {
            union { unsigned u; float f; } lo, hi;
            lo.u = w[k] << 16; hi.u = w[k] & 0xffff0000u;
            v[i*8 + k*2]     = lo.f;
            v[i*8 + k*2 + 1] = hi.f;
        }
    }
    float mx = v[0];
    #pragma unroll
    for (int j = 1; j < 32; ++j) mx = fmaxf(mx, v[j]);
    #pragma unroll
    for (int o = 1; o < 64; o <<= 1) mx = fmaxf(mx, __shfl_xor(mx, o));
    float s = 0.f;
    #pragma unroll
    for (int j = 0; j < 32; ++j) { v[j] = expf(v[j] - mx); s += v[j]; }
    #pragma unroll
    for (int o = 1; o < 64; o <<= 1) s += __shfl_xor(s, o);
    float inv = 1.f / s;
    #pragma unroll
    for (int i = 0; i < 4; ++i) {
        unsigned* w = reinterpret_cast<unsigned*>(&u[i]);
        #pragma unroll
        for (int k = 0; k < 4; ++k) {
            unsigned lo = f2bf(v[i*8 + k*2] * inv);
            unsigned hi = f2bf(v[i*8 + k*2 + 1] * inv);
            w[k] = lo | (hi << 16);
        }
    }
    #pragma unroll
    for (int i = 0; i < 4; ++i) p[i] = u[i];
}

__global__ __launch_bounds__(256) void ln_gelu(ushort_t* h1,
        const float* __restrict__ g, const float* __restrict__ b) {
    __shared__ float red[4];
    ushort_t* p = h1 + (size_t)blockIdx.x * 2048 + threadIdx.x * 8;
    ushort4 a = reinterpret_cast<const ushort4*>(p)[0];
    ushort4 c = reinterpret_cast<const ushort4*>(p)[1];
    float v[8] = { bf2f(a.x), bf2f(a.y), bf2f(a.z), bf2f(a.w),
                   bf2f(c.x), bf2f(c.y), bf2f(c.z), bf2f(c.w) };
    float s = 0.f, ss = 0.f;
    #pragma unroll
    for (int j = 0; j < 8; ++j) { s += v[j]; ss += v[j]*v[j]; }
    s  = blk_red(s, 0, red);
    ss = blk_red(ss, 0, red);
    float mu = s * (1.f / 2048.f);
    float var = ss * (1.f / 2048.f) - mu * mu;
    float rstd = rsqrtf(var + LNEPS);
    int c0 = threadIdx.x * 8;
    ushort_t o[8];
    #pragma unroll
    for (int j = 0; j < 8; ++j) {
        float xn = (v[j] - mu) * rstd * g[c0 + j] + b[c0 + j];
        float ge = 0.5f * xn * (1.f + erff(xn * 0.70710678118654752f));
        o[j] = f2bf(ge);
    }
    ushort4 o1 = { o[0], o[1], o[2], o[3] };
    ushort4 o2 = { o[4], o[5], o[6], o[7] };
    reinterpret_cast<ushort4*>(p)[0] = o1;
    reinterpret_cast<ushort4*>(p)[1] = o2;
}

// out = LN(x + gate*integ); gate bf16, integ bf16
__global__ __launch_bounds__(256) void final_ln(const float* __restrict__ x,
        const ushort_t* __restrict__ gate, const ushort_t* __restrict__ integ,
        const float* __restrict__ g, const float* __restrict__ b,
        float* __restrict__ out) {
    __shared__ float red[4];
    size_t base = (size_t)blockIdx.x * HDIM + threadIdx.x * 4;
    float4 xv = *reinterpret_cast<const float4*>(x + base);
    ushort4 gv = *reinterpret_cast<const ushort4*>(gate + base);
    ushort4 iv = *reinterpret_cast<const ushort4*>(integ + base);
    float v[4] = { xv.x + bf2f(gv.x)*bf2f(iv.x), xv.y + bf2f(gv.y)*bf2f(iv.y),
                   xv.z + bf2f(gv.z)*bf2f(iv.z), xv.w + bf2f(gv.w)*bf2f(iv.w) };
    float s = v[0]+v[1]+v[2]+v[3];
    float ss = v[0]*v[0]+v[1]*v[1]+v[2]*v[2]+v[3]*v[3];
    s  = blk_red(s, 0, red);
    ss = blk_red(ss, 0, red);
    float mu = s * (1.f / HDIM);
    float var = ss * (1.f / HDIM) - mu * mu;
    float rstd = rsqrtf(var + LNEPS);
    int c = threadIdx.x * 4;
    float4 o;
    o.x = (v[0] - mu) * rstd * g[c+0] + b[c+0];
    o.y = (v[1] - mu) * rstd * g[c+1] + b[c+1];
    o.z = (v[2] - mu) * rstd * g[c+2] + b[c+2];
    o.w = (v[3] - mu) * rstd * g[c+3] + b[c+3];
    *reinterpret_cast<float4*>(out + base) = o;
}

// ---------- 128x128 MFMA GEMM (proven) + T1 XCD swizzle ----------
// EPI: 0=f32, 1=bf16, 2=sigmoid->f32, 3=split gate(bf16 sigmoid,ldc)/h1(bf16,2048)
template<int EPI, int BIAS>
__global__ __launch_bounds__(256, 2)
void gemm_bt(const ushort_t* __restrict__ A, const ushort_t* __restrict__ B,
             const float* __restrict__ bias, void* __restrict__ Cv,
             void* __restrict__ Cv2, const float* __restrict__ bias2,
             int K, int lda, int ldb, int ldc,
             long long sA1, long long sA2, long long sAz,
             long long sB1, long long sB2, long long sBz,
             long long sC1, long long sC2, long long sCz,
             int z2n, int zbase, float scale)
{
    __shared__ __align__(16) ushort_t As[8192];
    __shared__ __align__(16) ushort_t Bs[8192];
    const int zz = blockIdx.z;
    const int zg = zz + zbase;
    const int z1 = zg / z2n, z2 = zg - z1 * z2n;
    A += (size_t)(z1 * sA1 + z2 * sA2 + zz * sAz);
    B += (size_t)(z1 * sB1 + z2 * sB2 + zz * sBz);
    const size_t cOff = (size_t)(z1 * sC1 + z2 * sC2 + zz * sCz);

    const int nwg = gridDim.x * gridDim.y;
    const int wg  = blockIdx.y * gridDim.x + blockIdx.x;
    const int q8  = nwg >> 3, r8 = nwg & 7;
    const int xcd = wg & 7, lo = wg >> 3;
    const int wgid = (xcd < r8 ? xcd * (q8 + 1) : r8 * (q8 + 1) + (xcd - r8) * q8) + lo;
    const int m0 = (wgid / gridDim.x) * 128, n0 = (wgid % gridDim.x) * 128;

    const int tid = threadIdx.x;
    const int w = tid >> 6, l = tid & 63;
    const int wm = w >> 1, wn = w & 1;

    f32x4 acc[4][4] = {};
    const int srow = l >> 3;
    const int scol = ((l & 7) ^ srow) << 3;

    for (int k0 = 0; k0 < K; k0 += 64) {
        #pragma unroll
        for (int i = 0; i < 4; ++i) {
            const int c = i * 4 + w;
            const int row = c * 8 + srow;
            const ushort_t* ga = A + (size_t)(m0 + row) * lda + (k0 + scol);
            const ushort_t* gb = B + (size_t)(n0 + row) * ldb + (k0 + scol);
            __builtin_amdgcn_global_load_lds((GVoid*)ga, (LVoid*)(As + c * 512), 16, 0, 0);
            __builtin_amdgcn_global_load_lds((GVoid*)gb, (LVoid*)(Bs + c * 512), 16, 0, 0);
        }
        __syncthreads();
        #pragma unroll
        for (int kk = 0; kk < 2; ++kk) {
            bf16x8 af[4], bfv[4];
            #pragma unroll
            for (int m = 0; m < 4; ++m) {
                const int row = wm * 64 + m * 16 + (l & 15);
                const int cb = ((kk * 64) + ((l >> 4) * 16)) ^ ((row & 7) << 4);
                af[m] = *reinterpret_cast<const bf16x8*>(
                    reinterpret_cast<const char*>(As) + row * 128 + cb);
            }
            #pragma unroll
            for (int n = 0; n < 4; ++n) {
                const int row = wn * 64 + n * 16 + (l & 15);
                const int cb = ((kk * 64) + ((l >> 4) * 16)) ^ ((row & 7) << 4);
                bfv[n] = *reinterpret_cast<const bf16x8*>(
                    reinterpret_cast<const char*>(Bs) + row * 128 + cb);
            }
            #pragma unroll
            for (int m = 0; m < 4; ++m)
                #pragma unroll
                for (int n = 0; n < 4; ++n)
                    acc[m][n] = __builtin_amdgcn_mfma_f32_16x16x32_bf16(
                        af[m], bfv[n], acc[m][n], 0, 0, 0);
        }
        __syncthreads();
    }

    #pragma unroll
    for (int m = 0; m < 4; ++m) {
        const int grow = m0 + wm * 64 + m * 16 + ((l >> 4) << 2);
        #pragma unroll
        for (int n = 0; n < 4; ++n) {
            const int gcol = n0 + wn * 64 + n * 16 + (l & 15);
            float bc = (BIAS == 1) ? bias[gcol] : 0.f;
            #pragma unroll
            for (int j = 0; j < 4; ++j) {
                if (EPI == 3) {
                    float v = acc[m][n][j];
                    if (gcol < 1024) {
                        v += bias[gcol];
                        v = 1.f / (1.f + expf(-v));
                        ((ushort_t*)Cv)[(size_t)(grow + j) * ldc + gcol] = f2bf(v);
                    } else {
                        v += bias2[gcol - 1024];
                        ((ushort_t*)Cv2)[(size_t)(grow + j) * 2048 + (gcol - 1024)] = f2bf(v);
                    }
                } else {
                    float v = acc[m][n][j] * scale;
                    if (BIAS == 1) v += bc;
                    if (BIAS == 2) v += bias[grow + j];
                    if (EPI == 2) v = 1.f / (1.f + expf(-v));
                    const size_t off = cOff + (size_t)(grow + j) * ldc + gcol;
                    if (EPI == 1) ((ushort_t*)Cv)[off] = f2bf(v);
                    else          ((float*)Cv)[off]    = v;
                }
            }
        }
    }
}

// ---------- host ----------
extern "C" void kernel_launch(void* const* d_in, const int* in_sizes, int n_in,
                              void* d_out, int out_size, void* d_ws, size_t ws_size,
                              hipStream_t stream) {
    const float* x          = (const float*)d_in[0];
    const float* mem_keys   = (const float*)d_in[1];
    const float* importance = (const float*)d_in[2];
    const float* recency    = (const float*)d_in[3];
    const float* access_cnt = (const float*)d_in[4];
    const float* Wq         = (const float*)d_in[5];
    const float* bq         = (const float*)d_in[6];
    const float* in_w       = (const float*)d_in[7];
    const float* in_b       = (const float*)d_in[8];
    const float* out_w      = (const float*)d_in[9];
    const float* out_b      = (const float*)d_in[10];
    const float* gate_w     = (const float*)d_in[11];
    const float* gate_b     = (const float*)d_in[12];
    const float* int_w1     = (const float*)d_in[13];
    const float* int_b1     = (const float*)d_in[14];
    const float* int_ln_g   = (const float*)d_in[15];
    const float* int_ln_b   = (const float*)d_in[16];
    const float* int_w2     = (const float*)d_in[17];
    const float* int_b2     = (const float*)d_in[18];
    const float* ln1_g      = (const float*)d_in[19];
    const float* ln1_b      = (const float*)d_in[20];
    const float* ln2_g      = (const float*)d_in[21];
    const float* ln2_b      = (const float*)d_in[22];
    const float* sel_params = (const float*)d_in[23];

    char* ws = (char*)d_ws;
    size_t off = 0;
    auto alloc = [&](size_t bytes) -> char* {
        char* p = ws + off;
        off = (off + bytes + 255) & ~(size_t)255;
        return p;
    };

    float*    sel      = (float*)alloc(MMEM * 4);
    int*      idx      = (int*)alloc(TOPK * 4);
    float*    beff     = (float*)alloc(1024 * 4);
    ushort_t* wqT_bf   = (ushort_t*)alloc((size_t)1048576 * 2);
    ushort_t* weff_bf  = (ushort_t*)alloc((size_t)1048576 * 2);
    ushort_t* inw_bf   = (ushort_t*)alloc((size_t)3145728 * 2);
    ushort_t* outw_bf  = (ushort_t*)alloc((size_t)1048576 * 2);
    ushort_t* gw3      = (ushort_t*)alloc((size_t)6291456 * 2);   // [gate_w;int_w1] 3072x2048
    ushort_t* intw2_bf = (ushort_t*)alloc((size_t)2097152 * 2);
    ushort_t* mem_n    = (ushort_t*)alloc((size_t)TOPK * HDIM * 2);
    ushort_t* Kbuf     = (ushort_t*)alloc((size_t)TOPK * HDIM * 2);
    ushort_t* Vt       = (ushort_t*)alloc((size_t)HDIM * TOPK * 2);
    ushort_t* cat      = (ushort_t*)alloc((size_t)NROWS * 2048 * 2);
    ushort_t* qQ       = (ushort_t*)alloc((size_t)NROWS * 2048 * 2);
    ushort_t* Qbuf     = qQ + (size_t)NROWS * HDIM;
    ushort_t* h1       = qQ;                            // Q dead by h1 time
    ushort_t* ctx      = (ushort_t*)alloc((size_t)NROWS * HDIM * 2);
    ushort_t* integ    = ctx;

    int NC = 16;
    while (NC > 1 && off + (size_t)NC * 8388608 > ws_size) NC >>= 1;
    ushort_t* scores = (ushort_t*)alloc((size_t)NC * 8388608);
    ushort_t* gatev  = scores;                          // scores dead before gate

    cvt_t_bf16<<<dim3(16,16), 256, 0, stream>>>(Wq, wqT_bf);
    cvt_all<<<12288, 256, 0, stream>>>(in_w, out_w, gate_w, int_w1, int_w2,
                                       inw_bf, outw_bf, gw3, intw2_bf);
    cvt_x_cat<<<8192, 256, 0, stream>>>(x, cat);
    bias_fold<<<1024, 256, 0, stream>>>(in_w, bq, in_b, beff);

    // W_eff = wq . (Wq^T)^T
    gemm_bt<1,0><<<dim3(8,8,1), 256, 0, stream>>>(inw_bf, wqT_bf, nullptr, weff_bf,
        nullptr, nullptr, 1024, 1024, 1024, 1024, 0,0,0, 0,0,0, 0,0,0, 1, 0, 1.f);

    sel_prep<<<1, 256, 0, stream>>>(sel_params, importance, recency, access_cnt, sel);
    topk_rank<<<MMEM/32, 256, 0, stream>>>(sel, idx);
    gather_ln<<<TOPK, 256, 0, stream>>>(mem_keys, idx, ln1_g, ln1_b, mem_n);

    // Q = x @ W_eff^T + beff
    gemm_bt<1,1><<<dim3(8,64,1), 256, 0, stream>>>(cat, weff_bf, beff, Qbuf,
        nullptr, nullptr, 1024, 2048, 1024, 1024, 0,0,0, 0,0,0, 0,0,0, 1, 0, 1.f);
    // K = mem_n @ wk^T + bki
    gemm_bt<1,1><<<dim3(8,16,1), 256, 0, stream>>>(mem_n, inw_bf + 1048576, in_b + 1024,
        Kbuf, nullptr, nullptr, 1024, 1024, 1024, 1024, 0,0,0, 0,0,0, 0,0,0, 1, 0, 1.f);
    // Vt = wv @ mem_n^T + bvi(per-row)
    gemm_bt<1,2><<<dim3(16,8,1), 256, 0, stream>>>(inw_bf + 2097152, mem_n, in_b + 2048,
        Vt, nullptr, nullptr, 1024, 1024, 1024, 2048, 0,0,0, 0,0,0, 0,0,0, 1, 0, 1.f);

    for (int c0 = 0; c0 < 16; c0 += NC) {
        gemm_bt<1,0><<<dim3(16,16,NC), 256, 0, stream>>>(Qbuf, Kbuf, nullptr, scores,
            nullptr, nullptr, 256, 1024, 1024, 2048,
            2097152, 256, 0,  0, 256, 0,  0, 0, 4194304, 4, c0, 0.0625f);
        softmax_rows<<<NC * 512, 256, 0, stream>>>(scores);
        gemm_bt<1,0><<<dim3(2,16,NC), 256, 0, stream>>>(scores, Vt, nullptr, ctx,
            nullptr, nullptr, 2048, 2048, 2048, 1024,
            0, 0, 4194304,  0, 524288, 0,  2097152, 256, 0, 4, c0, 1.f);
    }

    // attn_out -> cat[:, 1024:]
    gemm_bt<1,1><<<dim3(8,64,1), 256, 0, stream>>>(ctx, outw_bf, out_b,
        (void*)(cat + 1024), nullptr, nullptr, 1024, 1024, 1024, 2048,
        0,0,0, 0,0,0, 0,0,0, 1, 0, 1.f);

    // fused: [gate | h1] = cat @ [gate_w; int_w1]^T ; gate=sigmoid->bf16, h1->bf16
    gemm_bt<3,0><<<dim3(24,64,1), 256, 0, stream>>>(cat, gw3, gate_b, gatev,
        h1, int_b1, 2048, 2048, 2048, 1024, 0,0,0, 0,0,0, 0,0,0, 1, 0, 1.f);

    ln_gelu<<<NROWS, 256, 0, stream>>>(h1, int_ln_g, int_ln_b);
    // integ = h1 @ int_w2^T + int_b2
    gemm_bt<1,1><<<dim3(8,64,1), 256, 0, stream>>>(h1, intw2_bf, int_b2, integ,
        nullptr, nullptr, 2048, 2048, 2048, 1024, 0,0,0, 0,0,0, 0,0,0, 1, 0, 1.f);
    final_ln<<<NROWS, 256, 0, stream>>>(x, gatev, integ, ln2_g, ln2_b, (float*)d_out);
}

// Round 8
// 572.548 us; speedup vs baseline: 1.2478x; 1.0202x over previous
//
#include <hip/hip_runtime.h>

#define HDIM 1024
#define MMEM 8192
#define TOPK 2048
#define NROWS 8192
#define LNEPS 1e-5f

typedef unsigned short ushort_t;
typedef __bf16 bf16x8 __attribute__((ext_vector_type(8)));
typedef float f32x4 __attribute__((ext_vector_type(4)));
typedef __attribute__((address_space(1))) const void GVoid;
typedef __attribute__((address_space(3))) void LVoid;

// ---------- helpers ----------
__device__ __forceinline__ ushort_t f2bf(float f) {
    union { float f; unsigned u; } c; c.f = f;
    unsigned r = c.u + 0x7fffu + ((c.u >> 16) & 1u);
    return (ushort_t)(r >> 16);
}
__device__ __forceinline__ float bf2f(ushort_t u) {
    union { unsigned u; float f; } c; c.u = ((unsigned)u) << 16; return c.f;
}
__device__ __forceinline__ float blk_red(float v, int op, float* red) {
    #pragma unroll
    for (int o = 32; o; o >>= 1) {
        float u = __shfl_down(v, o);
        v = op ? fmaxf(v, u) : v + u;
    }
    if ((threadIdx.x & 63) == 0) red[threadIdx.x >> 6] = v;
    __syncthreads();
    float r = op ? fmaxf(fmaxf(red[0], red[1]), fmaxf(red[2], red[3]))
                 : (red[0] + red[1]) + (red[2] + red[3]);
    __syncthreads();
    return r;
}

// ---------- small prep kernels ----------
__global__ __launch_bounds__(256) void sel_prep(const float* __restrict__ sp,
        const float* __restrict__ imp, const float* __restrict__ rec,
        const float* __restrict__ ac, float* __restrict__ sel) {
    __shared__ float red[4];
    float p0 = sp[0], p1 = sp[1], p2 = sp[2];
    float mx = fmaxf(p0, fmaxf(p1, p2));
    float e0 = expf(p0 - mx), e1 = expf(p1 - mx), e2 = expf(p2 - mx);
    float inv = 1.f / (e0 + e1 + e2);
    float w0 = e0 * inv, w1 = e1 * inv, w2 = e2 * inv;
    float m = -1e30f;
    for (int i = threadIdx.x; i < MMEM; i += 256) m = fmaxf(m, ac[i]);
    m = blk_red(m, 1, red);
    float rinv = 1.f / m;
    for (int i = threadIdx.x; i < MMEM; i += 256)
        sel[i] = w0 * imp[i] + w1 * rec[i] + w2 * (ac[i] * rinv);
}

__global__ __launch_bounds__(256) void topk_rank(const float* __restrict__ sel,
                                                 int* __restrict__ idx) {
    __shared__ float s[MMEM];
    __shared__ int pc[256];
    for (int t = threadIdx.x; t < MMEM / 4; t += 256)
        reinterpret_cast<float4*>(s)[t] = reinterpret_cast<const float4*>(sel)[t];
    __syncthreads();
    const int li = threadIdx.x & 31;
    const int jc = threadIdx.x >> 5;
    const int i  = blockIdx.x * 32 + li;
    const float si = s[i];
    int cnt = 0;
    const float4* sv = reinterpret_cast<const float4*>(s) + jc * 256;
    #pragma unroll 4
    for (int t = 0; t < 256; ++t) {
        float4 v = sv[t];
        int j0 = jc * 1024 + t * 4;
        cnt += (v.x > si) || (v.x == si && (j0 + 0) < i);
        cnt += (v.y > si) || (v.y == si && (j0 + 1) < i);
        cnt += (v.z > si) || (v.z == si && (j0 + 2) < i);
        cnt += (v.w > si) || (v.w == si && (j0 + 3) < i);
    }
    pc[threadIdx.x] = cnt;
    __syncthreads();
    if (threadIdx.x < 32) {
        int r = 0;
        #pragma unroll
        for (int c = 0; c < 8; ++c) r += pc[c * 32 + threadIdx.x];
        if (r < TOPK) idx[r] = blockIdx.x * 32 + threadIdx.x;
    }
}

__global__ __launch_bounds__(256) void gather_ln(const float* __restrict__ mem_keys,
        const int* __restrict__ idx, const float* __restrict__ g,
        const float* __restrict__ b, ushort_t* __restrict__ out) {
    __shared__ float red[4];
    int src = idx[blockIdx.x] & (MMEM - 1);
    const float* x = mem_keys + (size_t)src * HDIM;
    float4 v = reinterpret_cast<const float4*>(x)[threadIdx.x];
    float s = v.x + v.y + v.z + v.w;
    float ss = v.x*v.x + v.y*v.y + v.z*v.z + v.w*v.w;
    s  = blk_red(s, 0, red);
    ss = blk_red(ss, 0, red);
    float mu = s * (1.f / HDIM);
    float var = ss * (1.f / HDIM) - mu * mu;
    float rstd = rsqrtf(var + LNEPS);
    int c = threadIdx.x * 4;
    ushort4 o;
    o.x = f2bf((v.x - mu) * rstd * g[c+0] + b[c+0]);
    o.y = f2bf((v.y - mu) * rstd * g[c+1] + b[c+1]);
    o.z = f2bf((v.z - mu) * rstd * g[c+2] + b[c+2]);
    o.w = f2bf((v.w - mu) * rstd * g[c+3] + b[c+3]);
    *reinterpret_cast<ushort4*>(out + (size_t)blockIdx.x * HDIM + c) = o;
}

// generic f32 -> bf16 (grid = elems/1024)
__global__ __launch_bounds__(256) void cvt_bf16(const float* __restrict__ in,
                                                ushort_t* __restrict__ out) {
    size_t i = ((size_t)blockIdx.x * 256 + threadIdx.x) * 4;
    float4 v = *reinterpret_cast<const float4*>(in + i);
    ushort4 o = { f2bf(v.x), f2bf(v.y), f2bf(v.z), f2bf(v.w) };
    *reinterpret_cast<ushort4*>(out + i) = o;
}

// merged weight conversion: in_w(3072), gate_w->gw3(2048), int_w1->gw3+(4096), int_w2(2048)
__global__ __launch_bounds__(256) void cvt_all(const float* __restrict__ in_w,
        const float* __restrict__ gate_w, const float* __restrict__ int_w1,
        const float* __restrict__ int_w2,
        ushort_t* __restrict__ inw_bf, ushort_t* __restrict__ gw3,
        ushort_t* __restrict__ intw2_bf) {
    const int b = blockIdx.x;
    const float* src; ushort_t* dst; int rel;
    if      (b < 3072) { src = in_w;   dst = inw_bf;        rel = b; }
    else if (b < 5120) { src = gate_w; dst = gw3;           rel = b - 3072; }
    else if (b < 9216) { src = int_w1; dst = gw3 + 2097152; rel = b - 5120; }
    else               { src = int_w2; dst = intw2_bf;      rel = b - 9216; }
    size_t i = ((size_t)rel * 256 + threadIdx.x) * 4;
    float4 v = *reinterpret_cast<const float4*>(src + i);
    ushort4 o = { f2bf(v.x), f2bf(v.y), f2bf(v.z), f2bf(v.w) };
    *reinterpret_cast<ushort4*>(dst + i) = o;
}

// 1024x1024 f32 -> bf16 TRANSPOSED
__global__ __launch_bounds__(256) void cvt_t_bf16(const float* __restrict__ in,
                                                  ushort_t* __restrict__ out) {
    __shared__ ushort_t t[64][65];
    const int bx = blockIdx.x * 64, by = blockIdx.y * 64;
    const int r = threadIdx.x >> 4, c4 = (threadIdx.x & 15) << 2;
    #pragma unroll
    for (int rr = 0; rr < 64; rr += 16) {
        float4 v = *reinterpret_cast<const float4*>(in + (size_t)(by + r + rr) * 1024 + bx + c4);
        t[r + rr][c4 + 0] = f2bf(v.x);
        t[r + rr][c4 + 1] = f2bf(v.y);
        t[r + rr][c4 + 2] = f2bf(v.z);
        t[r + rr][c4 + 3] = f2bf(v.w);
    }
    __syncthreads();
    #pragma unroll
    for (int rr = 0; rr < 64; rr += 16) {
        const int i = r + rr;
        ushort4 o = { t[c4 + 0][i], t[c4 + 1][i], t[c4 + 2][i], t[c4 + 3][i] };
        *reinterpret_cast<ushort4*>(out + (size_t)(bx + i) * 1024 + by + c4) = o;
    }
}

// beff[n] = dot(wq[n,:], bq) + bqi[n]
__global__ __launch_bounds__(256) void bias_fold(const float* __restrict__ wq,
        const float* __restrict__ bq, const float* __restrict__ bqi,
        float* __restrict__ beff) {
    __shared__ float red[4];
    const float4 wv = reinterpret_cast<const float4*>(wq + (size_t)blockIdx.x * 1024)[threadIdx.x];
    const float4 bv = reinterpret_cast<const float4*>(bq)[threadIdx.x];
    float s = wv.x*bv.x + wv.y*bv.y + wv.z*bv.z + wv.w*bv.w;
    s = blk_red(s, 0, red);
    if (threadIdx.x == 0) beff[blockIdx.x] = s + bqi[blockIdx.x];
}

// beff3[j] = ([gate_b;int_b1])[j] + dot(W_right[j,:], out_b); grid 3072
__global__ __launch_bounds__(256) void bias_fold3(const float* __restrict__ gate_w,
        const float* __restrict__ int_w1, const float* __restrict__ gate_b,
        const float* __restrict__ int_b1, const float* __restrict__ out_b,
        float* __restrict__ beff3) {
    __shared__ float red[4];
    const int j = blockIdx.x;
    const float* wrow = (j < 1024 ? gate_w + (size_t)j * 2048
                                  : int_w1 + (size_t)(j - 1024) * 2048) + 1024;
    const float4 wv = reinterpret_cast<const float4*>(wrow)[threadIdx.x];
    const float4 bv = reinterpret_cast<const float4*>(out_b)[threadIdx.x];
    float s = wv.x*bv.x + wv.y*bv.y + wv.z*bv.z + wv.w*bv.w;
    s = blk_red(s, 0, red);
    if (threadIdx.x == 0)
        beff3[j] = s + (j < 1024 ? gate_b[j] : int_b1[j - 1024]);
}

// wave-per-row softmax over 2048 bf16; grid = nrows/4
__global__ __launch_bounds__(256) void softmax_rows(ushort_t* __restrict__ sc) {
    const int row = blockIdx.x * 4 + (threadIdx.x >> 6);
    const int l = threadIdx.x & 63;
    uint4* p = reinterpret_cast<uint4*>(sc + (size_t)row * 2048 + l * 32);
    uint4 u[4];
    #pragma unroll
    for (int i = 0; i < 4; ++i) u[i] = p[i];
    float v[32];
    #pragma unroll
    for (int i = 0; i < 4; ++i) {
        unsigned* w = reinterpret_cast<unsigned*>(&u[i]);
        #pragma unroll
        for (int k = 0; k < 4; ++k) {
            union { unsigned u; float f; } lo, hi;
            lo.u = w[k] << 16; hi.u = w[k] & 0xffff0000u;
            v[i*8 + k*2]     = lo.f;
            v[i*8 + k*2 + 1] = hi.f;
        }
    }
    float mx = v[0];
    #pragma unroll
    for (int j = 1; j < 32; ++j) mx = fmaxf(mx, v[j]);
    #pragma unroll
    for (int o = 1; o < 64; o <<= 1) mx = fmaxf(mx, __shfl_xor(mx, o));
    float s = 0.f;
    #pragma unroll
    for (int j = 0; j < 32; ++j) { v[j] = __expf(v[j] - mx); s += v[j]; }
    #pragma unroll
    for (int o = 1; o < 64; o <<= 1) s += __shfl_xor(s, o);
    float inv = 1.f / s;
    #pragma unroll
    for (int i = 0; i < 4; ++i) {
        unsigned* w = reinterpret_cast<unsigned*>(&u[i]);
        #pragma unroll
        for (int k = 0; k < 4; ++k) {
            unsigned lo = f2bf(v[i*8 + k*2] * inv);
            unsigned hi = f2bf(v[i*8 + k*2 + 1] * inv);
            w[k] = lo | (hi << 16);
        }
    }
    #pragma unroll
    for (int i = 0; i < 4; ++i) p[i] = u[i];
}

__global__ __launch_bounds__(256) void ln_gelu(ushort_t* h1,
        const float* __restrict__ g, const float* __restrict__ b) {
    __shared__ float red[4];
    ushort_t* p = h1 + (size_t)blockIdx.x * 2048 + threadIdx.x * 8;
    ushort4 a = reinterpret_cast<const ushort4*>(p)[0];
    ushort4 c = reinterpret_cast<const ushort4*>(p)[1];
    float v[8] = { bf2f(a.x), bf2f(a.y), bf2f(a.z), bf2f(a.w),
                   bf2f(c.x), bf2f(c.y), bf2f(c.z), bf2f(c.w) };
    float s = 0.f, ss = 0.f;
    #pragma unroll
    for (int j = 0; j < 8; ++j) { s += v[j]; ss += v[j]*v[j]; }
    s  = blk_red(s, 0, red);
    ss = blk_red(ss, 0, red);
    float mu = s * (1.f / 2048.f);
    float var = ss * (1.f / 2048.f) - mu * mu;
    float rstd = rsqrtf(var + LNEPS);
    int c0 = threadIdx.x * 8;
    ushort_t o[8];
    #pragma unroll
    for (int j = 0; j < 8; ++j) {
        float xn = (v[j] - mu) * rstd * g[c0 + j] + b[c0 + j];
        float ge = 0.5f * xn * (1.f + erff(xn * 0.70710678118654752f));
        o[j] = f2bf(ge);
    }
    ushort4 o1 = { o[0], o[1], o[2], o[3] };
    ushort4 o2 = { o[4], o[5], o[6], o[7] };
    reinterpret_cast<ushort4*>(p)[0] = o1;
    reinterpret_cast<ushort4*>(p)[1] = o2;
}

__global__ __launch_bounds__(256) void final_ln(const float* __restrict__ x,
        const ushort_t* __restrict__ gate, const ushort_t* __restrict__ integ,
        const float* __restrict__ g, const float* __restrict__ b,
        float* __restrict__ out) {
    __shared__ float red[4];
    size_t base = (size_t)blockIdx.x * HDIM + threadIdx.x * 4;
    float4 xv = *reinterpret_cast<const float4*>(x + base);
    ushort4 gv = *reinterpret_cast<const ushort4*>(gate + base);
    ushort4 iv = *reinterpret_cast<const ushort4*>(integ + base);
    float v[4] = { xv.x + bf2f(gv.x)*bf2f(iv.x), xv.y + bf2f(gv.y)*bf2f(iv.y),
                   xv.z + bf2f(gv.z)*bf2f(iv.z), xv.w + bf2f(gv.w)*bf2f(iv.w) };
    float s = v[0]+v[1]+v[2]+v[3];
    float ss = v[0]*v[0]+v[1]*v[1]+v[2]*v[2]+v[3]*v[3];
    s  = blk_red(s, 0, red);
    ss = blk_red(ss, 0, red);
    float mu = s * (1.f / HDIM);
    float var = ss * (1.f / HDIM) - mu * mu;
    float rstd = rsqrtf(var + LNEPS);
    int c = threadIdx.x * 4;
    float4 o;
    o.x = (v[0] - mu) * rstd * g[c+0] + b[c+0];
    o.y = (v[1] - mu) * rstd * g[c+1] + b[c+1];
    o.z = (v[2] - mu) * rstd * g[c+2] + b[c+2];
    o.w = (v[3] - mu) * rstd * g[c+3] + b[c+3];
    *reinterpret_cast<float4*>(out + base) = o;
}

// ---------- 128x128 MFMA GEMM + T1 XCD swizzle + split-K dual operand ----------
// EPI: 0=f32, 1=bf16, 2=sigmoid->f32, 3=split gate(bf16 sigmoid,ldc)/h1(bf16,2048)
// SPLIT: k>=1024 reads A2/B2 (k-1024), strides lda2/ldb2
template<int EPI, int BIAS, int SPLIT>
__global__ __launch_bounds__(256, 2)
void gemm_bt(const ushort_t* __restrict__ A, const ushort_t* __restrict__ B,
             const ushort_t* __restrict__ A2, const ushort_t* __restrict__ B2,
             int lda2, int ldb2,
             const float* __restrict__ bias, void* __restrict__ Cv,
             void* __restrict__ Cv2, const float* __restrict__ bias2,
             int K, int lda, int ldb, int ldc,
             long long sA1, long long sA2s, long long sAz,
             long long sB1, long long sB2s, long long sBz,
             long long sC1, long long sC2s, long long sCz,
             int z2n, int zbase, float scale)
{
    __shared__ __align__(16) ushort_t As[8192];
    __shared__ __align__(16) ushort_t Bs[8192];
    const int zz = blockIdx.z;
    const int zg = zz + zbase;
    const int z1 = zg / z2n, z2 = zg - z1 * z2n;
    A += (size_t)(z1 * sA1 + z2 * sA2s + zz * sAz);
    B += (size_t)(z1 * sB1 + z2 * sB2s + zz * sBz);
    const size_t cOff = (size_t)(z1 * sC1 + z2 * sC2s + zz * sCz);

    const int nwg = gridDim.x * gridDim.y;
    const int wg  = blockIdx.y * gridDim.x + blockIdx.x;
    const int q8  = nwg >> 3, r8 = nwg & 7;
    const int xcd = wg & 7, lo = wg >> 3;
    const int wgid = (xcd < r8 ? xcd * (q8 + 1) : r8 * (q8 + 1) + (xcd - r8) * q8) + lo;
    const int m0 = (wgid / gridDim.x) * 128, n0 = (wgid % gridDim.x) * 128;

    const int tid = threadIdx.x;
    const int w = tid >> 6, l = tid & 63;
    const int wm = w >> 1, wn = w & 1;

    f32x4 acc[4][4] = {};
    const int srow = l >> 3;
    const int scol = ((l & 7) ^ srow) << 3;

    for (int k0 = 0; k0 < K; k0 += 64) {
        const ushort_t* Ab = A; const ushort_t* Bb = B;
        int la = lda, lb = ldb, kk0 = k0;
        if (SPLIT && k0 >= 1024) { Ab = A2; Bb = B2; la = lda2; lb = ldb2; kk0 = k0 - 1024; }
        #pragma unroll
        for (int i = 0; i < 4; ++i) {
            const int c = i * 4 + w;
            const int row = c * 8 + srow;
            const ushort_t* ga = Ab + (size_t)(m0 + row) * la + (kk0 + scol);
            const ushort_t* gb = Bb + (size_t)(n0 + row) * lb + (kk0 + scol);
            __builtin_amdgcn_global_load_lds((GVoid*)ga, (LVoid*)(As + c * 512), 16, 0, 0);
            __builtin_amdgcn_global_load_lds((GVoid*)gb, (LVoid*)(Bs + c * 512), 16, 0, 0);
        }
        __syncthreads();
        #pragma unroll
        for (int kk = 0; kk < 2; ++kk) {
            bf16x8 af[4], bfv[4];
            #pragma unroll
            for (int m = 0; m < 4; ++m) {
                const int row = wm * 64 + m * 16 + (l & 15);
                const int cb = ((kk * 64) + ((l >> 4) * 16)) ^ ((row & 7) << 4);
                af[m] = *reinterpret_cast<const bf16x8*>(
                    reinterpret_cast<const char*>(As) + row * 128 + cb);
            }
            #pragma unroll
            for (int n = 0; n < 4; ++n) {
                const int row = wn * 64 + n * 16 + (l & 15);
                const int cb = ((kk * 64) + ((l >> 4) * 16)) ^ ((row & 7) << 4);
                bfv[n] = *reinterpret_cast<const bf16x8*>(
                    reinterpret_cast<const char*>(Bs) + row * 128 + cb);
            }
            #pragma unroll
            for (int m = 0; m < 4; ++m)
                #pragma unroll
                for (int n = 0; n < 4; ++n)
                    acc[m][n] = __builtin_amdgcn_mfma_f32_16x16x32_bf16(
                        af[m], bfv[n], acc[m][n], 0, 0, 0);
        }
        __syncthreads();
    }

    #pragma unroll
    for (int m = 0; m < 4; ++m) {
        const int grow = m0 + wm * 64 + m * 16 + ((l >> 4) << 2);
        #pragma unroll
        for (int n = 0; n < 4; ++n) {
            const int gcol = n0 + wn * 64 + n * 16 + (l & 15);
            float bc = (BIAS == 1) ? bias[gcol] : 0.f;
            #pragma unroll
            for (int j = 0; j < 4; ++j) {
                if (EPI == 3) {
                    float v = acc[m][n][j];
                    if (gcol < 1024) {
                        v += bias[gcol];
                        v = 1.f / (1.f + __expf(-v));
                        ((ushort_t*)Cv)[(size_t)(grow + j) * ldc + gcol] = f2bf(v);
                    } else {
                        v += bias2[gcol - 1024];
                        ((ushort_t*)Cv2)[(size_t)(grow + j) * 2048 + (gcol - 1024)] = f2bf(v);
                    }
                } else {
                    float v = acc[m][n][j] * scale;
                    if (BIAS == 1) v += bc;
                    if (BIAS == 2) v += bias[grow + j];
                    if (EPI == 2) v = 1.f / (1.f + __expf(-v));
                    const size_t off = cOff + (size_t)(grow + j) * ldc + gcol;
                    if (EPI == 1) ((ushort_t*)Cv)[off] = f2bf(v);
                    else          ((float*)Cv)[off]    = v;
                }
            }
        }
    }
}

// ---------- host ----------
extern "C" void kernel_launch(void* const* d_in, const int* in_sizes, int n_in,
                              void* d_out, int out_size, void* d_ws, size_t ws_size,
                              hipStream_t stream) {
    const float* x          = (const float*)d_in[0];
    const float* mem_keys   = (const float*)d_in[1];
    const float* importance = (const float*)d_in[2];
    const float* recency    = (const float*)d_in[3];
    const float* access_cnt = (const float*)d_in[4];
    const float* Wq         = (const float*)d_in[5];
    const float* bq         = (const float*)d_in[6];
    const float* in_w       = (const float*)d_in[7];
    const float* in_b       = (const float*)d_in[8];
    const float* out_w      = (const float*)d_in[9];
    const float* out_b      = (const float*)d_in[10];
    const float* gate_w     = (const float*)d_in[11];
    const float* gate_b     = (const float*)d_in[12];
    const float* int_w1     = (const float*)d_in[13];
    const float* int_b1     = (const float*)d_in[14];
    const float* int_ln_g   = (const float*)d_in[15];
    const float* int_ln_b   = (const float*)d_in[16];
    const float* int_w2     = (const float*)d_in[17];
    const float* int_b2     = (const float*)d_in[18];
    const float* ln1_g      = (const float*)d_in[19];
    const float* ln1_b      = (const float*)d_in[20];
    const float* ln2_g      = (const float*)d_in[21];
    const float* ln2_b      = (const float*)d_in[22];
    const float* sel_params = (const float*)d_in[23];

    char* ws = (char*)d_ws;
    size_t off = 0;
    auto alloc = [&](size_t bytes) -> char* {
        char* p = ws + off;
        off = (off + bytes + 255) & ~(size_t)255;
        return p;
    };

    float*    sel      = (float*)alloc(MMEM * 4);
    int*      idx      = (int*)alloc(TOPK * 4);
    float*    beff     = (float*)alloc(1024 * 4);
    float*    beff3    = (float*)alloc(3072 * 4);
    ushort_t* wqT_bf   = (ushort_t*)alloc((size_t)1048576 * 2);
    ushort_t* outwT_bf = (ushort_t*)alloc((size_t)1048576 * 2);
    ushort_t* weff_bf  = (ushort_t*)alloc((size_t)1048576 * 2);
    ushort_t* inw_bf   = (ushort_t*)alloc((size_t)3145728 * 2);
    ushort_t* gw3      = (ushort_t*)alloc((size_t)6291456 * 2);   // [gate_w;int_w1] 3072x2048
    ushort_t* wfold3   = (ushort_t*)alloc((size_t)3145728 * 2);   // [gw_a;w1_a]@out_w 3072x1024
    ushort_t* intw2_bf = (ushort_t*)alloc((size_t)2097152 * 2);
    ushort_t* mem_n    = (ushort_t*)alloc((size_t)TOPK * HDIM * 2);
    ushort_t* Kbuf     = (ushort_t*)alloc((size_t)TOPK * HDIM * 2);
    ushort_t* Vt       = (ushort_t*)alloc((size_t)HDIM * TOPK * 2);
    ushort_t* xbf      = (ushort_t*)alloc((size_t)NROWS * HDIM * 2);   // 16 MB
    ushort_t* qQ       = (ushort_t*)alloc((size_t)NROWS * 2048 * 2);   // 32 MB
    ushort_t* Qbuf     = qQ + (size_t)NROWS * HDIM;
    ushort_t* h1       = qQ;                            // Q dead by h1 time
    ushort_t* ctx      = (ushort_t*)alloc((size_t)NROWS * HDIM * 2);
    ushort_t* integ    = ctx;                           // ctx dead after fused gemm

    int NC = 16;
    while (NC > 1 && off + (size_t)NC * 8388608 > ws_size) NC >>= 1;
    ushort_t* scores = (ushort_t*)alloc((size_t)NC * 8388608);
    ushort_t* gatev  = scores;                          // scores dead before gate

    cvt_t_bf16<<<dim3(16,16), 256, 0, stream>>>(Wq, wqT_bf);
    cvt_t_bf16<<<dim3(16,16), 256, 0, stream>>>(out_w, outwT_bf);
    cvt_all<<<11264, 256, 0, stream>>>(in_w, gate_w, int_w1, int_w2,
                                       inw_bf, gw3, intw2_bf);
    cvt_bf16<<<8192, 256, 0, stream>>>(x, xbf);
    bias_fold<<<1024, 256, 0, stream>>>(in_w, bq, in_b, beff);
    bias_fold3<<<3072, 256, 0, stream>>>(gate_w, int_w1, gate_b, int_b1, out_b, beff3);

    // W_eff = wq . Wq  (via Wq^T as B)
    gemm_bt<1,0,0><<<dim3(8,8,1), 256, 0, stream>>>(inw_bf, wqT_bf,
        nullptr, nullptr, 0, 0, nullptr, weff_bf, nullptr, nullptr,
        1024, 1024, 1024, 1024, 0,0,0, 0,0,0, 0,0,0, 1, 0, 1.f);
    // wfold3 = gw3[:,1024:] @ out_w  (via out_w^T as B)
    gemm_bt<1,0,0><<<dim3(8,24,1), 256, 0, stream>>>(gw3 + 1024, outwT_bf,
        nullptr, nullptr, 0, 0, nullptr, wfold3, nullptr, nullptr,
        1024, 2048, 1024, 1024, 0,0,0, 0,0,0, 0,0,0, 1, 0, 1.f);

    sel_prep<<<1, 256, 0, stream>>>(sel_params, importance, recency, access_cnt, sel);
    topk_rank<<<MMEM/32, 256, 0, stream>>>(sel, idx);
    gather_ln<<<TOPK, 256, 0, stream>>>(mem_keys, idx, ln1_g, ln1_b, mem_n);

    // Q = x @ W_eff^T + beff
    gemm_bt<1,1,0><<<dim3(8,64,1), 256, 0, stream>>>(xbf, weff_bf,
        nullptr, nullptr, 0, 0, beff, Qbuf, nullptr, nullptr,
        1024, 1024, 1024, 1024, 0,0,0, 0,0,0, 0,0,0, 1, 0, 1.f);
    // K = mem_n @ wk^T + bki
    gemm_bt<1,1,0><<<dim3(8,16,1), 256, 0, stream>>>(mem_n, inw_bf + 1048576,
        nullptr, nullptr, 0, 0, in_b + 1024, Kbuf, nullptr, nullptr,
        1024, 1024, 1024, 1024, 0,0,0, 0,0,0, 0,0,0, 1, 0, 1.f);
    // Vt = wv @ mem_n^T + bvi(per-row)
    gemm_bt<1,2,0><<<dim3(16,8,1), 256, 0, stream>>>(inw_bf + 2097152, mem_n,
        nullptr, nullptr, 0, 0, in_b + 2048, Vt, nullptr, nullptr,
        1024, 1024, 1024, 2048, 0,0,0, 0,0,0, 0,0,0, 1, 0, 1.f);

    for (int c0 = 0; c0 < 16; c0 += NC) {
        gemm_bt<1,0,0><<<dim3(16,16,NC), 256, 0, stream>>>(Qbuf, Kbuf,
            nullptr, nullptr, 0, 0, nullptr, scores, nullptr, nullptr,
            256, 1024, 1024, 2048,
            2097152, 256, 0,  0, 256, 0,  0, 0, 4194304, 4, c0, 0.0625f);
        softmax_rows<<<NC * 512, 256, 0, stream>>>(scores);
        gemm_bt<1,0,0><<<dim3(2,16,NC), 256, 0, stream>>>(scores, Vt,
            nullptr, nullptr, 0, 0, nullptr, ctx, nullptr, nullptr,
            2048, 2048, 2048, 1024,
            0, 0, 4194304,  0, 524288, 0,  2097152, 256, 0, 4, c0, 1.f);
    }

    // fused: [gate | h1] = x@gw3_left^T + ctx@wfold3^T + beff3
    gemm_bt<3,0,1><<<dim3(24,64,1), 256, 0, stream>>>(xbf, gw3,
        ctx, wfold3, 1024, 1024, beff3, gatev, h1, beff3 + 1024,
        2048, 1024, 2048, 1024, 0,0,0, 0,0,0, 0,0,0, 1, 0, 1.f);

    ln_gelu<<<NROWS, 256, 0, stream>>>(h1, int_ln_g, int_ln_b);
    // integ = h1 @ int_w2^T + int_b2
    gemm_bt<1,1,0><<<dim3(8,64,1), 256, 0, stream>>>(h1, intw2_bf,
        nullptr, nullptr, 0, 0, int_b2, integ, nullptr, nullptr,
        2048, 2048, 2048, 1024, 0,0,0, 0,0,0, 0,0,0, 1, 0, 1.f);
    final_ln<<<NROWS, 256, 0, stream>>>(x, gatev, integ, ln2_g, ln2_b, (float*)d_out);
}